// Round 1
// baseline (422.318 us; speedup 1.0000x reference)
//
#include <hip/hip_runtime.h>

typedef _Float16 f16;
typedef f16 half8 __attribute__((ext_vector_type(8)));
typedef float f32x4 __attribute__((ext_vector_type(4)));

#define MFMA16(a, b, c) __builtin_amdgcn_mfma_f32_16x16x32_f16((a), (b), (c), 0, 0, 0)

static constexpr int B = 8, C = 256, CI = 128, N = 6272, M = 1568, MP = 1600;

// f16-element offsets into workspace (~71 MB). Y aliases phiF (consumed by k_pool).
static constexpr size_t oXT = 0;                         // [B][N][C]   x transposed, f16
static constexpr size_t oQ  = (size_t)B * N * C;         // [B][N][CI]  theta (log2e folded at attn load)
static constexpr size_t oPF = oQ  + (size_t)B * N * CI;  // [B][N][CI]  phi full-res; later Y
static constexpr size_t oGF = oPF + (size_t)B * N * CI;  // [B][N][CI]  g full-res
static constexpr size_t oPP = oGF + (size_t)B * N * CI;  // [B][MP][CI] phi pooled (K), pad zeroed
static constexpr size_t oGT = oPP + (size_t)B * MP * CI; // [B][CI][MP] g pooled transposed (V), pad zeroed
static constexpr size_t oW  = oGT + (size_t)B * MP * CI; // 4*32768 f16 weights: theta|phi|g|W

static __device__ __forceinline__ half8 hmax8(half8 a, half8 b) {
    half8 r;
#pragma unroll
    for (int j = 0; j < 8; j++) r[j] = a[j] > b[j] ? a[j] : b[j];
    return r;
}

// max across the 16 consecutive lanes of a DPP row (our 16-lane "quad" groups)
static __device__ __forceinline__ float rowmax16(float x) {
    int t;
    t = __builtin_amdgcn_update_dpp(__float_as_int(x), __float_as_int(x), 0x121, 0xF, 0xF, false);
    x = fmaxf(x, __int_as_float(t));
    t = __builtin_amdgcn_update_dpp(__float_as_int(x), __float_as_int(x), 0x122, 0xF, 0xF, false);
    x = fmaxf(x, __int_as_float(t));
    t = __builtin_amdgcn_update_dpp(__float_as_int(x), __float_as_int(x), 0x124, 0xF, 0xF, false);
    x = fmaxf(x, __int_as_float(t));
    t = __builtin_amdgcn_update_dpp(__float_as_int(x), __float_as_int(x), 0x128, 0xF, 0xF, false);
    x = fmaxf(x, __int_as_float(t));
    return x;
}

// ---------------- weight cast fp32 -> f16 ----------------
__global__ void k_prep(const float* tw, const float* pw, const float* gw,
                       const float* Ww, f16* dst) {
    int i = blockIdx.x * 256 + threadIdx.x;   // 0..131071
    int s = i >> 15, j = i & 32767;
    float v;
    if (s == 0) v = tw[j];
    else if (s == 1) v = pw[j];
    else if (s == 2) v = gw[j];
    else v = Ww[j];
    dst[i] = (f16)v;
}

// ---------------- x[b][c][n] fp32 -> xT[b][n][c] f16 ----------------
// grid (8, 196, 8): b in blockIdx.x so batch b lands on XCD b (round-robin by linear id)
__global__ void k_trans(const float* x, f16* xT) {
    __shared__ float tile[32][33];
    int b = blockIdx.x, nt = blockIdx.y, ct = blockIdx.z;
    int tx = threadIdx.x, ty = threadIdx.y;
#pragma unroll
    for (int i = 0; i < 4; i++) {
        int c = ct * 32 + ty + i * 8;
        tile[ty + i * 8][tx] = x[(size_t)(b * C + c) * N + nt * 32 + tx];
    }
    __syncthreads();
#pragma unroll
    for (int i = 0; i < 4; i++) {
        int n = nt * 32 + ty + i * 8;
        xT[(size_t)(b * N + n) * C + ct * 32 + tx] = (f16)tile[tx][ty + i * 8];
    }
}

// ---------------- projection GEMM: out[b][n][ci] = xT[b][n][:] . w16[ci][:] + bias ----------------
// grid (8, 49): b = blockIdx.x (XCD-local xT), n-tile = blockIdx.y
__global__ __launch_bounds__(256) void k_proj(const f16* __restrict__ xT,
                                              const f16* __restrict__ w16,
                                              const float* __restrict__ bias,
                                              f16* __restrict__ out) {
    __shared__ f16 xs[128 * 72];   // [128 n][64 k] pad 8
    __shared__ f16 ws[128 * 72];   // [128 ci][64 k] pad 8
    int b = blockIdx.x, n0 = blockIdx.y * 128;
    int tid = threadIdx.x, w = tid >> 6, lane = tid & 63, ln = lane & 15, quad = lane >> 4;
    f32x4 acc[2][8];
#pragma unroll
    for (int rb = 0; rb < 2; rb++)
#pragma unroll
        for (int cb = 0; cb < 8; cb++) acc[rb][cb] = (f32x4){0.f, 0.f, 0.f, 0.f};

    for (int kc = 0; kc < 4; kc++) {
#pragma unroll
        for (int i = 0; i < 4; i++) {
            int qq = tid + i * 256;              // 0..1023
            int row = qq >> 3, coff = (qq & 7) * 8;
            *(int4*)&xs[row * 72 + coff] =
                *(const int4*)&xT[(size_t)(b * N + n0 + row) * C + kc * 64 + coff];
            *(int4*)&ws[row * 72 + coff] =
                *(const int4*)&w16[(size_t)row * C + kc * 64 + coff];
        }
        __syncthreads();
#pragma unroll
        for (int ks = 0; ks < 2; ks++) {
            half8 a0 = *(const half8*)&xs[(w * 32 + ln) * 72 + ks * 32 + quad * 8];
            half8 a1 = *(const half8*)&xs[(w * 32 + 16 + ln) * 72 + ks * 32 + quad * 8];
#pragma unroll
            for (int cb = 0; cb < 8; cb++) {
                half8 bf = *(const half8*)&ws[(cb * 16 + ln) * 72 + ks * 32 + quad * 8];
                acc[0][cb] = MFMA16(a0, bf, acc[0][cb]);
                acc[1][cb] = MFMA16(a1, bf, acc[1][cb]);
            }
        }
        __syncthreads();
    }
#pragma unroll
    for (int cb = 0; cb < 8; cb++) {
        float bv = bias[cb * 16 + ln];
#pragma unroll
        for (int rb = 0; rb < 2; rb++) {
#pragma unroll
            for (int r = 0; r < 4; r++) {
                int n = n0 + w * 32 + rb * 16 + quad * 4 + r;
                out[(size_t)(b * N + n) * CI + cb * 16 + ln] = (f16)(acc[rb][cb][r] + bv);
            }
        }
    }
}

// ---------------- 2x2 spatial maxpool; K as [m][ci], V as [ci][m] (coalesced via LDS transpose) ----
// grid (8, 25): b = blockIdx.x
__global__ __launch_bounds__(256) void k_pool(const f16* __restrict__ phiF, const f16* __restrict__ gF,
                                              f16* __restrict__ phiP, f16* __restrict__ gPT) {
    __shared__ f16 gt[128 * 72];   // [128 ci][64 m] pad 8
    int b = blockIdx.x, mt = blockIdx.y;   // mt 0..24 over MP=1600
    int tid = threadIdx.x;
#pragma unroll
    for (int i = 0; i < 4; i++) {
        int qq = tid + i * 256;            // 0..1023
        int ml = qq >> 4, coff = (qq & 15) * 8;
        int m = mt * 64 + ml;
        half8 pv, gv;
        if (m < M) {
            int t = m / 196, rr = m % 196, hp = rr / 14, wp = rr % 14;
            int nb = t * 784 + hp * 56 + wp * 2;
            size_t base = ((size_t)(b * N) + nb) * CI + coff;
            half8 p0 = *(const half8*)&phiF[base];
            half8 p1 = *(const half8*)&phiF[base + CI];
            half8 p2 = *(const half8*)&phiF[base + 28 * CI];
            half8 p3 = *(const half8*)&phiF[base + 29 * CI];
            pv = hmax8(hmax8(p0, p1), hmax8(p2, p3));
            half8 g0 = *(const half8*)&gF[base];
            half8 g1 = *(const half8*)&gF[base + CI];
            half8 g2 = *(const half8*)&gF[base + 28 * CI];
            half8 g3 = *(const half8*)&gF[base + 29 * CI];
            gv = hmax8(hmax8(g0, g1), hmax8(g2, g3));
        } else {
#pragma unroll
            for (int j = 0; j < 8; j++) { pv[j] = (f16)0.f; gv[j] = (f16)0.f; }
        }
        *(half8*)&phiP[((size_t)b * MP + m) * CI + coff] = pv;
#pragma unroll
        for (int j = 0; j < 8; j++) gt[(coff + j) * 72 + ml] = gv[j];
    }
    __syncthreads();
#pragma unroll
    for (int i = 0; i < 4; i++) {
        int qq = tid + i * 256;
        int ci = qq >> 3, moff = (qq & 7) * 8;
        *(int4*)&gPT[((size_t)(b * CI) + ci) * MP + mt * 64 + moff] = *(const int4*)&gt[ci * 72 + moff];
    }
}

// ---------------- flash attention: y[b][n][ci] ----------------
// v2: QBLK=64 (4 waves x 16 q-rows), grid (8, 98) -> ~3 blocks/CU, batch->XCD swizzle,
//     register prefetch of next K/V tile (latency hides under compute), defer-rescale (THR=8, log2
//     domain), setprio around MFMA clusters.
__global__ __launch_bounds__(256, 3) void k_attn(const f16* __restrict__ q,
                                                 const f16* __restrict__ kk,
                                                 const f16* __restrict__ v,
                                                 f16* __restrict__ y) {
    __shared__ f16 Ks[64 * 136];     // [64 m][128 d] pad 8
    __shared__ f16 Vs[128 * 72];     // [128 ci][64 m] pad 8
    __shared__ f16 Ps[4 * 16 * 72];  // per-wave [16 q][64 m] pad 8
    int b = blockIdx.x, n0 = blockIdx.y * 64;
    int tid = threadIdx.x, w = tid >> 6, lane = tid & 63, ln = lane & 15, quad = lane >> 4;
    int wq = n0 + w * 16;
    f16* Pw = &Ps[w * 16 * 72];

    // staging geometry (constant per thread); row advances by i*16 (K) / i*32 (V)
    int kr = tid >> 4, kc = (tid & 15) * 8;
    int vr = tid >> 3, vc = (tid & 7) * 8;
    const f16* kbase = kk + ((size_t)b * MP + kr) * CI + kc;
    const f16* vbase = v + ((size_t)(b * CI) + vr) * MP + vc;

    // prologue: prefetch tile 0 into registers
    int4 kpf[4], vpf[4];
#pragma unroll
    for (int i = 0; i < 4; i++) {
        kpf[i] = *(const int4*)(kbase + (size_t)i * 16 * CI);
        vpf[i] = *(const int4*)(vbase + (size_t)i * 32 * MP);
    }

    // Q fragments in registers, pre-scaled by log2(e) so softmax is pure exp2
    half8 qf[4];
#pragma unroll
    for (int ks = 0; ks < 4; ks++) {
        qf[ks] = *(const half8*)&q[(size_t)(b * N + wq + ln) * CI + ks * 32 + quad * 8];
#pragma unroll
        for (int j = 0; j < 8; j++) qf[ks][j] *= (f16)1.4426950408889634f;
    }

    f32x4 O[8], Osum = (f32x4){0.f, 0.f, 0.f, 0.f};
#pragma unroll
    for (int cb = 0; cb < 8; cb++) O[cb] = (f32x4){0.f, 0.f, 0.f, 0.f};
    float mi[4] = {-1e30f, -1e30f, -1e30f, -1e30f};

    for (int mc = 0; mc < 25; mc++) {
        __syncthreads();                      // previous compute done reading Ks/Vs
#pragma unroll
        for (int i = 0; i < 4; i++) {         // regs -> LDS (vmcnt wait was hidden under compute)
            *(int4*)&Ks[(kr + i * 16) * 136 + kc] = kpf[i];
            *(int4*)&Vs[(vr + i * 32) * 72 + vc] = vpf[i];
        }
        __syncthreads();
        if (mc < 24) {                        // issue next tile's loads; consumed next iteration
#pragma unroll
            for (int i = 0; i < 4; i++) {
                kpf[i] = *(const int4*)(kbase + ((size_t)(mc + 1) * 64 + (size_t)i * 16) * CI);
                vpf[i] = *(const int4*)(vbase + (size_t)(mc + 1) * 64 + (size_t)i * 32 * MP);
            }
        }

        // ---- QK^T: 16 MFMA ----
        f32x4 S[4];
        __builtin_amdgcn_s_setprio(1);
#pragma unroll
        for (int mt = 0; mt < 4; mt++) {
            f32x4 s = (f32x4){0.f, 0.f, 0.f, 0.f};
#pragma unroll
            for (int ks = 0; ks < 4; ks++) {
                half8 kb = *(const half8*)&Ks[(mt * 16 + ln) * 136 + ks * 32 + quad * 8];
                s = MFMA16(qf[ks], kb, s);
            }
            S[mt] = s;
        }
        __builtin_amdgcn_s_setprio(0);

        // ---- online softmax (log2 domain), defer-rescale when max grows <= 8 ----
#pragma unroll
        for (int r = 0; r < 4; r++) {
            float vm = fmaxf(fmaxf(S[0][r], S[1][r]), fmaxf(S[2][r], S[3][r]));
            vm = rowmax16(vm);
            if (__ballot(vm > mi[r] + 8.f)) {          // wave-uniform; rare after warm-up
                float mnew = fmaxf(mi[r], vm);
                float alpha = __builtin_amdgcn_exp2f(mi[r] - mnew);
                mi[r] = mnew;
#pragma unroll
                for (int cb = 0; cb < 8; cb++) O[cb][r] *= alpha;
                Osum[r] *= alpha;
            }
#pragma unroll
            for (int mt = 0; mt < 4; mt++) {
                float p = __builtin_amdgcn_exp2f(S[mt][r] - mi[r]);   // bounded by 2^8
                Pw[(quad * 4 + r) * 72 + mt * 16 + ln] = (f16)p;
            }
        }

        // ---- PV + ones-column rowsum: 18 MFMA ----
        __builtin_amdgcn_s_setprio(1);
#pragma unroll
        for (int ks = 0; ks < 2; ks++) {
            half8 a = *(const half8*)&Pw[ln * 72 + ks * 32 + quad * 8];
            f16 ov = (mc * 64 + ks * 32 < M) ? (f16)1.0f : (f16)0.0f;  // mask pad cols
            half8 on;
#pragma unroll
            for (int j = 0; j < 8; j++) on[j] = ov;
#pragma unroll
            for (int cb = 0; cb < 8; cb++) {
                half8 bv = *(const half8*)&Vs[(cb * 16 + ln) * 72 + ks * 32 + quad * 8];
                O[cb] = MFMA16(a, bv, O[cb]);
            }
            Osum = MFMA16(a, on, Osum);
        }
        __builtin_amdgcn_s_setprio(0);
    }

#pragma unroll
    for (int cb = 0; cb < 8; cb++)
#pragma unroll
        for (int r = 0; r < 4; r++) {
            int n = wq + quad * 4 + r;
            y[(size_t)(b * N + n) * CI + cb * 16 + ln] = (f16)(O[cb][r] / Osum[r]);
        }
}

// ---------------- final: out[b][c][n] = W.y + Wb + x ----------------
// grid (8, 98, 2): b = blockIdx.x, n-tile = blockIdx.y, c-half = blockIdx.z
__global__ __launch_bounds__(256) void k_final(const f16* __restrict__ y,
                                               const f16* __restrict__ Ww,
                                               const float* __restrict__ Wb,
                                               const float* __restrict__ x,
                                               float* __restrict__ out) {
    __shared__ f16 ys[64 * 136];    // [64 n][128 ci] pad 8
    __shared__ f16 Ws[128 * 136];   // [128 c][128 ci] pad 8
    int b = blockIdx.x, ch = blockIdx.z, n0 = blockIdx.y * 64;
    int tid = threadIdx.x, w = tid >> 6, lane = tid & 63, ln = lane & 15, quad = lane >> 4;
#pragma unroll
    for (int i = 0; i < 4; i++) {
        int qq = tid + i * 256; int row = qq >> 4, coff = (qq & 15) * 8;
        *(int4*)&ys[row * 136 + coff] =
            *(const int4*)&y[(size_t)(b * N + n0 + row) * CI + coff];
    }
#pragma unroll
    for (int i = 0; i < 8; i++) {
        int qq = tid + i * 256; int row = qq >> 4, coff = (qq & 15) * 8;
        *(int4*)&Ws[row * 136 + coff] =
            *(const int4*)&Ww[(size_t)(ch * 128 + row) * CI + coff];
    }
    __syncthreads();
    f32x4 acc[2][4];
#pragma unroll
    for (int rb = 0; rb < 2; rb++)
#pragma unroll
        for (int nb = 0; nb < 4; nb++) acc[rb][nb] = (f32x4){0.f, 0.f, 0.f, 0.f};
#pragma unroll
    for (int ks = 0; ks < 4; ks++) {
        half8 a0 = *(const half8*)&Ws[(w * 32 + ln) * 136 + ks * 32 + quad * 8];
        half8 a1 = *(const half8*)&Ws[(w * 32 + 16 + ln) * 136 + ks * 32 + quad * 8];
#pragma unroll
        for (int nb = 0; nb < 4; nb++) {
            half8 bf = *(const half8*)&ys[(nb * 16 + ln) * 136 + ks * 32 + quad * 8];
            acc[0][nb] = MFMA16(a0, bf, acc[0][nb]);
            acc[1][nb] = MFMA16(a1, bf, acc[1][nb]);
        }
    }
#pragma unroll
    for (int rb = 0; rb < 2; rb++) {
        int cbase = ch * 128 + w * 32 + rb * 16 + quad * 4;
#pragma unroll
        for (int nb = 0; nb < 4; nb++) {
#pragma unroll
            for (int r = 0; r < 4; r++) {
                int c = cbase + r;
                size_t addr = (size_t)(b * C + c) * N + n0 + nb * 16 + ln;
                out[addr] = acc[rb][nb][r] + Wb[c] + x[addr];
            }
        }
    }
}

extern "C" void kernel_launch(void* const* d_in, const int* in_sizes, int n_in,
                              void* d_out, int out_size, void* d_ws, size_t ws_size,
                              hipStream_t stream) {
    const float* x  = (const float*)d_in[0];
    const float* gw = (const float*)d_in[1];
    const float* gb = (const float*)d_in[2];
    const float* tw = (const float*)d_in[3];
    const float* tb = (const float*)d_in[4];
    const float* pw = (const float*)d_in[5];
    const float* pb = (const float*)d_in[6];
    const float* Ww = (const float*)d_in[7];
    const float* Wb = (const float*)d_in[8];
    float* out = (float*)d_out;
    f16* ws = (f16*)d_ws;

    f16* xT   = ws + oXT;
    f16* Q    = ws + oQ;
    f16* phiF = ws + oPF;
    f16* gF   = ws + oGF;
    f16* phiP = ws + oPP;
    f16* gPT  = ws + oGT;
    f16* Y    = ws + oPF;   // alias: phiF dead after k_pool
    f16* w16  = ws + oW;

    k_prep<<<512, 256, 0, stream>>>(tw, pw, gw, Ww, w16);
    k_trans<<<dim3(8, 196, 8), dim3(32, 8), 0, stream>>>(x, xT);
    k_proj<<<dim3(8, 49), 256, 0, stream>>>(xT, w16,         tb, Q);
    k_proj<<<dim3(8, 49), 256, 0, stream>>>(xT, w16 + 32768, pb, phiF);
    k_proj<<<dim3(8, 49), 256, 0, stream>>>(xT, w16 + 65536, gb, gF);
    k_pool<<<dim3(8, 25), 256, 0, stream>>>(phiF, gF, phiP, gPT);
    k_attn<<<dim3(8, 98), 256, 0, stream>>>(Q, phiP, gPT, Y);
    k_final<<<dim3(8, 98, 2), 256, 0, stream>>>(Y, w16 + 98304, Wb, x, out);
    (void)in_sizes; (void)n_in; (void)out_size; (void)ws_size;
}

// Round 2
// 315.644 us; speedup vs baseline: 1.3380x; 1.3380x over previous
//
#include <hip/hip_runtime.h>

typedef _Float16 f16;
typedef f16 half8 __attribute__((ext_vector_type(8)));
typedef float f32x4 __attribute__((ext_vector_type(4)));

#define MFMA16(a, b, c) __builtin_amdgcn_mfma_f32_16x16x32_f16((a), (b), (c), 0, 0, 0)

static constexpr int B = 8, C = 256, CI = 128, N = 6272, M = 1568, MP = 1600;

// f16-element offsets into workspace (~71 MB). Y aliases phiF (consumed by k_pool).
static constexpr size_t oXT = 0;                         // [B][N][C]   x transposed, f16
static constexpr size_t oQ  = (size_t)B * N * C;         // [B][N][CI]  theta (log2e folded at attn load)
static constexpr size_t oPF = oQ  + (size_t)B * N * CI;  // [B][N][CI]  phi full-res; later Y
static constexpr size_t oGF = oPF + (size_t)B * N * CI;  // [B][N][CI]  g full-res
static constexpr size_t oPP = oGF + (size_t)B * N * CI;  // [B][MP][CI] phi pooled (K), pad zeroed
static constexpr size_t oGT = oPP + (size_t)B * MP * CI; // [B][CI][MP] g pooled transposed (V), pad zeroed
static constexpr size_t oW  = oGT + (size_t)B * MP * CI; // 4*32768 f16 weights: theta|phi|g|W

static __device__ __forceinline__ half8 hmax8(half8 a, half8 b) {
    half8 r;
#pragma unroll
    for (int j = 0; j < 8; j++) r[j] = a[j] > b[j] ? a[j] : b[j];
    return r;
}

// max across the 16 consecutive lanes of a DPP row (our 16-lane "quad" groups)
static __device__ __forceinline__ float rowmax16(float x) {
    int t;
    t = __builtin_amdgcn_update_dpp(__float_as_int(x), __float_as_int(x), 0x121, 0xF, 0xF, false);
    x = fmaxf(x, __int_as_float(t));
    t = __builtin_amdgcn_update_dpp(__float_as_int(x), __float_as_int(x), 0x122, 0xF, 0xF, false);
    x = fmaxf(x, __int_as_float(t));
    t = __builtin_amdgcn_update_dpp(__float_as_int(x), __float_as_int(x), 0x124, 0xF, 0xF, false);
    x = fmaxf(x, __int_as_float(t));
    t = __builtin_amdgcn_update_dpp(__float_as_int(x), __float_as_int(x), 0x128, 0xF, 0xF, false);
    x = fmaxf(x, __int_as_float(t));
    return x;
}

// ---------------- weight cast fp32 -> f16 ----------------
__global__ void k_prep(const float* tw, const float* pw, const float* gw,
                       const float* Ww, f16* dst) {
    int i = blockIdx.x * 256 + threadIdx.x;   // 0..131071
    int s = i >> 15, j = i & 32767;
    float v;
    if (s == 0) v = tw[j];
    else if (s == 1) v = pw[j];
    else if (s == 2) v = gw[j];
    else v = Ww[j];
    dst[i] = (f16)v;
}

// ---------------- x[b][c][n] fp32 -> xT[b][n][c] f16 ----------------
// grid (8, 196, 8): b in blockIdx.x so batch b lands on XCD b (round-robin by linear id)
__global__ void k_trans(const float* x, f16* xT) {
    __shared__ float tile[32][33];
    int b = blockIdx.x, nt = blockIdx.y, ct = blockIdx.z;
    int tx = threadIdx.x, ty = threadIdx.y;
#pragma unroll
    for (int i = 0; i < 4; i++) {
        int c = ct * 32 + ty + i * 8;
        tile[ty + i * 8][tx] = x[(size_t)(b * C + c) * N + nt * 32 + tx];
    }
    __syncthreads();
#pragma unroll
    for (int i = 0; i < 4; i++) {
        int n = nt * 32 + ty + i * 8;
        xT[(size_t)(b * N + n) * C + ct * 32 + tx] = (f16)tile[tx][ty + i * 8];
    }
}

// ---------------- projection GEMM: out[b][n][ci] = xT[b][n][:] . w16[ci][:] + bias ----------------
// grid (8, 49): b = blockIdx.x (XCD-local xT), n-tile = blockIdx.y
__global__ __launch_bounds__(256) void k_proj(const f16* __restrict__ xT,
                                              const f16* __restrict__ w16,
                                              const float* __restrict__ bias,
                                              f16* __restrict__ out) {
    __shared__ f16 xs[128 * 72];   // [128 n][64 k] pad 8
    __shared__ f16 ws[128 * 72];   // [128 ci][64 k] pad 8
    int b = blockIdx.x, n0 = blockIdx.y * 128;
    int tid = threadIdx.x, w = tid >> 6, lane = tid & 63, ln = lane & 15, quad = lane >> 4;
    f32x4 acc[2][8];
#pragma unroll
    for (int rb = 0; rb < 2; rb++)
#pragma unroll
        for (int cb = 0; cb < 8; cb++) acc[rb][cb] = (f32x4){0.f, 0.f, 0.f, 0.f};

    for (int kc = 0; kc < 4; kc++) {
#pragma unroll
        for (int i = 0; i < 4; i++) {
            int qq = tid + i * 256;              // 0..1023
            int row = qq >> 3, coff = (qq & 7) * 8;
            *(int4*)&xs[row * 72 + coff] =
                *(const int4*)&xT[(size_t)(b * N + n0 + row) * C + kc * 64 + coff];
            *(int4*)&ws[row * 72 + coff] =
                *(const int4*)&w16[(size_t)row * C + kc * 64 + coff];
        }
        __syncthreads();
#pragma unroll
        for (int ks = 0; ks < 2; ks++) {
            half8 a0 = *(const half8*)&xs[(w * 32 + ln) * 72 + ks * 32 + quad * 8];
            half8 a1 = *(const half8*)&xs[(w * 32 + 16 + ln) * 72 + ks * 32 + quad * 8];
#pragma unroll
            for (int cb = 0; cb < 8; cb++) {
                half8 bf = *(const half8*)&ws[(cb * 16 + ln) * 72 + ks * 32 + quad * 8];
                acc[0][cb] = MFMA16(a0, bf, acc[0][cb]);
                acc[1][cb] = MFMA16(a1, bf, acc[1][cb]);
            }
        }
        __syncthreads();
    }
#pragma unroll
    for (int cb = 0; cb < 8; cb++) {
        float bv = bias[cb * 16 + ln];
#pragma unroll
        for (int rb = 0; rb < 2; rb++) {
#pragma unroll
            for (int r = 0; r < 4; r++) {
                int n = n0 + w * 32 + rb * 16 + quad * 4 + r;
                out[(size_t)(b * N + n) * CI + cb * 16 + ln] = (f16)(acc[rb][cb][r] + bv);
            }
        }
    }
}

// ---------------- 2x2 spatial maxpool; K as [m][ci], V as [ci][m] (coalesced via LDS transpose) ----
// grid (8, 25): b = blockIdx.x
__global__ __launch_bounds__(256) void k_pool(const f16* __restrict__ phiF, const f16* __restrict__ gF,
                                              f16* __restrict__ phiP, f16* __restrict__ gPT) {
    __shared__ f16 gt[128 * 72];   // [128 ci][64 m] pad 8
    int b = blockIdx.x, mt = blockIdx.y;   // mt 0..24 over MP=1600
    int tid = threadIdx.x;
#pragma unroll
    for (int i = 0; i < 4; i++) {
        int qq = tid + i * 256;            // 0..1023
        int ml = qq >> 4, coff = (qq & 15) * 8;
        int m = mt * 64 + ml;
        half8 pv, gv;
        if (m < M) {
            int t = m / 196, rr = m % 196, hp = rr / 14, wp = rr % 14;
            int nb = t * 784 + hp * 56 + wp * 2;
            size_t base = ((size_t)(b * N) + nb) * CI + coff;
            half8 p0 = *(const half8*)&phiF[base];
            half8 p1 = *(const half8*)&phiF[base + CI];
            half8 p2 = *(const half8*)&phiF[base + 28 * CI];
            half8 p3 = *(const half8*)&phiF[base + 29 * CI];
            pv = hmax8(hmax8(p0, p1), hmax8(p2, p3));
            half8 g0 = *(const half8*)&gF[base];
            half8 g1 = *(const half8*)&gF[base + CI];
            half8 g2 = *(const half8*)&gF[base + 28 * CI];
            half8 g3 = *(const half8*)&gF[base + 29 * CI];
            gv = hmax8(hmax8(g0, g1), hmax8(g2, g3));
        } else {
#pragma unroll
            for (int j = 0; j < 8; j++) { pv[j] = (f16)0.f; gv[j] = (f16)0.f; }
        }
        *(half8*)&phiP[((size_t)b * MP + m) * CI + coff] = pv;
#pragma unroll
        for (int j = 0; j < 8; j++) gt[(coff + j) * 72 + ml] = gv[j];
    }
    __syncthreads();
#pragma unroll
    for (int i = 0; i < 4; i++) {
        int qq = tid + i * 256;
        int ci = qq >> 3, moff = (qq & 7) * 8;
        *(int4*)&gPT[((size_t)(b * CI) + ci) * MP + mt * 64 + moff] = *(const int4*)&gt[ci * 72 + moff];
    }
}

// ---------------- flash attention: y[b][n][ci] ----------------
// v3: QBLK=64 (4 waves x 16 q-rows), grid (8, 98) -> 784 blocks, 3 blocks/CU, batch->XCD swizzle.
//     Direct global->LDS staging (round-0 pattern; the v2 register double-buffer spilled to
//     scratch: WRITE_SIZE 12.5 MB -> 420 MB). Defer-rescale (THR=8, log2 domain) + setprio kept.
__global__ __launch_bounds__(256, 3) void k_attn(const f16* __restrict__ q,
                                                 const f16* __restrict__ kk,
                                                 const f16* __restrict__ v,
                                                 f16* __restrict__ y) {
    __shared__ f16 Ks[64 * 136];     // [64 m][128 d] pad 8
    __shared__ f16 Vs[128 * 72];     // [128 ci][64 m] pad 8
    __shared__ f16 Ps[4 * 16 * 72];  // per-wave [16 q][64 m] pad 8
    int b = blockIdx.x, n0 = blockIdx.y * 64;
    int tid = threadIdx.x, w = tid >> 6, lane = tid & 63, ln = lane & 15, quad = lane >> 4;
    int wq = n0 + w * 16;
    f16* Pw = &Ps[w * 16 * 72];

    // Q fragments in registers, pre-scaled by log2(e) so softmax is pure exp2
    half8 qf[4];
#pragma unroll
    for (int ks = 0; ks < 4; ks++) {
        qf[ks] = *(const half8*)&q[(size_t)(b * N + wq + ln) * CI + ks * 32 + quad * 8];
#pragma unroll
        for (int j = 0; j < 8; j++) qf[ks][j] *= (f16)1.4426950408889634f;
    }

    f32x4 O[8], Osum = (f32x4){0.f, 0.f, 0.f, 0.f};
#pragma unroll
    for (int cb = 0; cb < 8; cb++) O[cb] = (f32x4){0.f, 0.f, 0.f, 0.f};
    float mi[4] = {-1e30f, -1e30f, -1e30f, -1e30f};

    for (int mc = 0; mc < 25; mc++) {
        // ---- stage K (16KB) + V (16KB), direct global->LDS ----
#pragma unroll
        for (int i = 0; i < 4; i++) {
            int qq = tid + i * 256;
            int kr = qq >> 4, kc = (qq & 15) * 8;
            *(int4*)&Ks[kr * 136 + kc] = *(const int4*)&kk[((size_t)b * MP + mc * 64 + kr) * CI + kc];
            int vr = qq >> 3, vc = (qq & 7) * 8;
            *(int4*)&Vs[vr * 72 + vc] = *(const int4*)&v[((size_t)(b * CI) + vr) * MP + mc * 64 + vc];
        }
        __syncthreads();

        // ---- QK^T: 16 MFMA ----
        f32x4 S[4];
        __builtin_amdgcn_s_setprio(1);
#pragma unroll
        for (int mt = 0; mt < 4; mt++) {
            f32x4 s = (f32x4){0.f, 0.f, 0.f, 0.f};
#pragma unroll
            for (int ks = 0; ks < 4; ks++) {
                half8 kb = *(const half8*)&Ks[(mt * 16 + ln) * 136 + ks * 32 + quad * 8];
                s = MFMA16(qf[ks], kb, s);
            }
            S[mt] = s;
        }
        __builtin_amdgcn_s_setprio(0);

        // ---- online softmax (log2 domain), defer-rescale when max grows <= 8 ----
#pragma unroll
        for (int r = 0; r < 4; r++) {
            float vm = fmaxf(fmaxf(S[0][r], S[1][r]), fmaxf(S[2][r], S[3][r]));
            vm = rowmax16(vm);
            if (__ballot(vm > mi[r] + 8.f)) {          // wave-uniform; rare after warm-up
                float mnew = fmaxf(mi[r], vm);
                float alpha = __builtin_amdgcn_exp2f(mi[r] - mnew);
                mi[r] = mnew;
#pragma unroll
                for (int cb = 0; cb < 8; cb++) O[cb][r] *= alpha;
                Osum[r] *= alpha;
            }
#pragma unroll
            for (int mt = 0; mt < 4; mt++) {
                float p = __builtin_amdgcn_exp2f(S[mt][r] - mi[r]);   // bounded by 2^8
                Pw[(quad * 4 + r) * 72 + mt * 16 + ln] = (f16)p;
            }
        }

        // ---- PV + ones-column rowsum: 18 MFMA ----
        __builtin_amdgcn_s_setprio(1);
#pragma unroll
        for (int ks = 0; ks < 2; ks++) {
            half8 a = *(const half8*)&Pw[ln * 72 + ks * 32 + quad * 8];
            f16 ov = (mc * 64 + ks * 32 < M) ? (f16)1.0f : (f16)0.0f;  // mask pad cols
            half8 on;
#pragma unroll
            for (int j = 0; j < 8; j++) on[j] = ov;
#pragma unroll
            for (int cb = 0; cb < 8; cb++) {
                half8 bv = *(const half8*)&Vs[(cb * 16 + ln) * 72 + ks * 32 + quad * 8];
                O[cb] = MFMA16(a, bv, O[cb]);
            }
            Osum = MFMA16(a, on, Osum);
        }
        __builtin_amdgcn_s_setprio(0);
        __syncthreads();
    }

#pragma unroll
    for (int cb = 0; cb < 8; cb++)
#pragma unroll
        for (int r = 0; r < 4; r++) {
            int n = wq + quad * 4 + r;
            y[(size_t)(b * N + n) * CI + cb * 16 + ln] = (f16)(O[cb][r] / Osum[r]);
        }
}

// ---------------- final: out[b][c][n] = W.y + Wb + x ----------------
// grid (8, 98, 2): b = blockIdx.x, n-tile = blockIdx.y, c-half = blockIdx.z
__global__ __launch_bounds__(256) void k_final(const f16* __restrict__ y,
                                               const f16* __restrict__ Ww,
                                               const float* __restrict__ Wb,
                                               const float* __restrict__ x,
                                               float* __restrict__ out) {
    __shared__ f16 ys[64 * 136];    // [64 n][128 ci] pad 8
    __shared__ f16 Ws[128 * 136];   // [128 c][128 ci] pad 8
    int b = blockIdx.x, ch = blockIdx.z, n0 = blockIdx.y * 64;
    int tid = threadIdx.x, w = tid >> 6, lane = tid & 63, ln = lane & 15, quad = lane >> 4;
#pragma unroll
    for (int i = 0; i < 4; i++) {
        int qq = tid + i * 256; int row = qq >> 4, coff = (qq & 15) * 8;
        *(int4*)&ys[row * 136 + coff] =
            *(const int4*)&y[(size_t)(b * N + n0 + row) * CI + coff];
    }
#pragma unroll
    for (int i = 0; i < 8; i++) {
        int qq = tid + i * 256; int row = qq >> 4, coff = (qq & 15) * 8;
        *(int4*)&Ws[row * 136 + coff] =
            *(const int4*)&Ww[(size_t)(ch * 128 + row) * CI + coff];
    }
    __syncthreads();
    f32x4 acc[2][4];
#pragma unroll
    for (int rb = 0; rb < 2; rb++)
#pragma unroll
        for (int nb = 0; nb < 4; nb++) acc[rb][nb] = (f32x4){0.f, 0.f, 0.f, 0.f};
#pragma unroll
    for (int ks = 0; ks < 4; ks++) {
        half8 a0 = *(const half8*)&Ws[(w * 32 + ln) * 136 + ks * 32 + quad * 8];
        half8 a1 = *(const half8*)&Ws[(w * 32 + 16 + ln) * 136 + ks * 32 + quad * 8];
#pragma unroll
        for (int nb = 0; nb < 4; nb++) {
            half8 bf = *(const half8*)&ys[(nb * 16 + ln) * 136 + ks * 32 + quad * 8];
            acc[0][nb] = MFMA16(a0, bf, acc[0][nb]);
            acc[1][nb] = MFMA16(a1, bf, acc[1][nb]);
        }
    }
#pragma unroll
    for (int rb = 0; rb < 2; rb++) {
        int cbase = ch * 128 + w * 32 + rb * 16 + quad * 4;
#pragma unroll
        for (int nb = 0; nb < 4; nb++) {
#pragma unroll
            for (int r = 0; r < 4; r++) {
                int c = cbase + r;
                size_t addr = (size_t)(b * C + c) * N + n0 + nb * 16 + ln;
                out[addr] = acc[rb][nb][r] + Wb[c] + x[addr];
            }
        }
    }
}

extern "C" void kernel_launch(void* const* d_in, const int* in_sizes, int n_in,
                              void* d_out, int out_size, void* d_ws, size_t ws_size,
                              hipStream_t stream) {
    const float* x  = (const float*)d_in[0];
    const float* gw = (const float*)d_in[1];
    const float* gb = (const float*)d_in[2];
    const float* tw = (const float*)d_in[3];
    const float* tb = (const float*)d_in[4];
    const float* pw = (const float*)d_in[5];
    const float* pb = (const float*)d_in[6];
    const float* Ww = (const float*)d_in[7];
    const float* Wb = (const float*)d_in[8];
    float* out = (float*)d_out;
    f16* ws = (f16*)d_ws;

    f16* xT   = ws + oXT;
    f16* Q    = ws + oQ;
    f16* phiF = ws + oPF;
    f16* gF   = ws + oGF;
    f16* phiP = ws + oPP;
    f16* gPT  = ws + oGT;
    f16* Y    = ws + oPF;   // alias: phiF dead after k_pool
    f16* w16  = ws + oW;

    k_prep<<<512, 256, 0, stream>>>(tw, pw, gw, Ww, w16);
    k_trans<<<dim3(8, 196, 8), dim3(32, 8), 0, stream>>>(x, xT);
    k_proj<<<dim3(8, 49), 256, 0, stream>>>(xT, w16,         tb, Q);
    k_proj<<<dim3(8, 49), 256, 0, stream>>>(xT, w16 + 32768, pb, phiF);
    k_proj<<<dim3(8, 49), 256, 0, stream>>>(xT, w16 + 65536, gb, gF);
    k_pool<<<dim3(8, 25), 256, 0, stream>>>(phiF, gF, phiP, gPT);
    k_attn<<<dim3(8, 98), 256, 0, stream>>>(Q, phiP, gPT, Y);
    k_final<<<dim3(8, 98, 2), 256, 0, stream>>>(Y, w16 + 98304, Wb, x, out);
    (void)in_sizes; (void)n_in; (void)out_size; (void)ws_size;
}

// Round 5
// 253.552 us; speedup vs baseline: 1.6656x; 1.2449x over previous
//
#include <hip/hip_runtime.h>

typedef _Float16 f16;
typedef f16 half8 __attribute__((ext_vector_type(8)));
typedef __fp16 fp16x2 __attribute__((ext_vector_type(2)));
typedef float f32x4 __attribute__((ext_vector_type(4)));
typedef float f32x16 __attribute__((ext_vector_type(16)));

#define MFMA16(a, b, c) __builtin_amdgcn_mfma_f32_16x16x32_f16((a), (b), (c), 0, 0, 0)
#define MFMA32(a, b, c) __builtin_amdgcn_mfma_f32_32x32x16_f16((a), (b), (c), 0, 0, 0)

static constexpr int B = 8, C = 256, CI = 128, N = 6272, M = 1568, MP = 1600;

// f16-element offsets into workspace (~71 MB). Y aliases phiF (consumed by k_pool).
static constexpr size_t oXT = 0;                         // [B][N][C]   x transposed, f16
static constexpr size_t oQ  = (size_t)B * N * C;         // [B][N][CI]  theta (log2e folded at attn load)
static constexpr size_t oPF = oQ  + (size_t)B * N * CI;  // [B][N][CI]  phi full-res; later Y
static constexpr size_t oGF = oPF + (size_t)B * N * CI;  // [B][N][CI]  g full-res
static constexpr size_t oPP = oGF + (size_t)B * N * CI;  // [B][MP][CI] phi pooled (K), pad zeroed
static constexpr size_t oGT = oPP + (size_t)B * MP * CI; // [B][CI][MP] g pooled transposed (V), pad zeroed
static constexpr size_t oW  = oGT + (size_t)B * MP * CI; // 4*32768 f16 weights: theta|phi|g|W

static __device__ __forceinline__ half8 hmax8(half8 a, half8 b) {
    half8 r;
#pragma unroll
    for (int j = 0; j < 8; j++) r[j] = a[j] > b[j] ? a[j] : b[j];
    return r;
}

static __device__ __forceinline__ int pk2(float a, float b) {
    union { fp16x2 h; int i; } u;
    u.h = __builtin_amdgcn_cvt_pkrtz(a, b);
    return u.i;
}

// ---------------- weight cast fp32 -> f16 ----------------
__global__ void k_prep(const float* tw, const float* pw, const float* gw,
                       const float* Ww, f16* dst) {
    int i = blockIdx.x * 256 + threadIdx.x;   // 0..131071
    int s = i >> 15, j = i & 32767;
    float v;
    if (s == 0) v = tw[j];
    else if (s == 1) v = pw[j];
    else if (s == 2) v = gw[j];
    else v = Ww[j];
    dst[i] = (f16)v;
}

// ---------------- x[b][c][n] fp32 -> xT[b][n][c] f16 ----------------
// grid (8, 196, 8): b in blockIdx.x so batch b lands on XCD b (round-robin by linear id)
__global__ void k_trans(const float* x, f16* xT) {
    __shared__ float tile[32][33];
    int b = blockIdx.x, nt = blockIdx.y, ct = blockIdx.z;
    int tx = threadIdx.x, ty = threadIdx.y;
#pragma unroll
    for (int i = 0; i < 4; i++) {
        int c = ct * 32 + ty + i * 8;
        tile[ty + i * 8][tx] = x[(size_t)(b * C + c) * N + nt * 32 + tx];
    }
    __syncthreads();
#pragma unroll
    for (int i = 0; i < 4; i++) {
        int n = nt * 32 + ty + i * 8;
        xT[(size_t)(b * N + n) * C + ct * 32 + tx] = (f16)tile[tx][ty + i * 8];
    }
}

// ---------------- projection GEMM: out[b][n][ci] = xT[b][n][:] . w16[ci][:] + bias ----------------
// grid (8, 49): b = blockIdx.x (XCD-local xT), n-tile = blockIdx.y
__global__ __launch_bounds__(256) void k_proj(const f16* __restrict__ xT,
                                              const f16* __restrict__ w16,
                                              const float* __restrict__ bias,
                                              f16* __restrict__ out) {
    __shared__ f16 xs[128 * 72];   // [128 n][64 k] pad 8
    __shared__ f16 ws[128 * 72];   // [128 ci][64 k] pad 8
    int b = blockIdx.x, n0 = blockIdx.y * 128;
    int tid = threadIdx.x, w = tid >> 6, lane = tid & 63, ln = lane & 15, quad = lane >> 4;
    f32x4 acc[2][8];
#pragma unroll
    for (int rb = 0; rb < 2; rb++)
#pragma unroll
        for (int cb = 0; cb < 8; cb++) acc[rb][cb] = (f32x4){0.f, 0.f, 0.f, 0.f};

    for (int kc = 0; kc < 4; kc++) {
#pragma unroll
        for (int i = 0; i < 4; i++) {
            int qq = tid + i * 256;              // 0..1023
            int row = qq >> 3, coff = (qq & 7) * 8;
            *(int4*)&xs[row * 72 + coff] =
                *(const int4*)&xT[(size_t)(b * N + n0 + row) * C + kc * 64 + coff];
            *(int4*)&ws[row * 72 + coff] =
                *(const int4*)&w16[(size_t)row * C + kc * 64 + coff];
        }
        __syncthreads();
#pragma unroll
        for (int ks = 0; ks < 2; ks++) {
            half8 a0 = *(const half8*)&xs[(w * 32 + ln) * 72 + ks * 32 + quad * 8];
            half8 a1 = *(const half8*)&xs[(w * 32 + 16 + ln) * 72 + ks * 32 + quad * 8];
#pragma unroll
            for (int cb = 0; cb < 8; cb++) {
                half8 bf = *(const half8*)&ws[(cb * 16 + ln) * 72 + ks * 32 + quad * 8];
                acc[0][cb] = MFMA16(a0, bf, acc[0][cb]);
                acc[1][cb] = MFMA16(a1, bf, acc[1][cb]);
            }
        }
        __syncthreads();
    }
#pragma unroll
    for (int cb = 0; cb < 8; cb++) {
        float bv = bias[cb * 16 + ln];
#pragma unroll
        for (int rb = 0; rb < 2; rb++) {
#pragma unroll
            for (int r = 0; r < 4; r++) {
                int n = n0 + w * 32 + rb * 16 + quad * 4 + r;
                out[(size_t)(b * N + n) * CI + cb * 16 + ln] = (f16)(acc[rb][cb][r] + bv);
            }
        }
    }
}

// ---------------- 2x2 spatial maxpool; K as [m][ci], V as [ci][m] (coalesced via LDS transpose) ----
// grid (8, 25): b = blockIdx.x
__global__ __launch_bounds__(256) void k_pool(const f16* __restrict__ phiF, const f16* __restrict__ gF,
                                              f16* __restrict__ phiP, f16* __restrict__ gPT) {
    __shared__ f16 gt[128 * 72];   // [128 ci][64 m] pad 8
    int b = blockIdx.x, mt = blockIdx.y;   // mt 0..24 over MP=1600
    int tid = threadIdx.x;
#pragma unroll
    for (int i = 0; i < 4; i++) {
        int qq = tid + i * 256;            // 0..1023
        int ml = qq >> 4, coff = (qq & 15) * 8;
        int m = mt * 64 + ml;
        half8 pv, gv;
        if (m < M) {
            int t = m / 196, rr = m % 196, hp = rr / 14, wp = rr % 14;
            int nb = t * 784 + hp * 56 + wp * 2;
            size_t base = ((size_t)(b * N) + nb) * CI + coff;
            half8 p0 = *(const half8*)&phiF[base];
            half8 p1 = *(const half8*)&phiF[base + CI];
            half8 p2 = *(const half8*)&phiF[base + 28 * CI];
            half8 p3 = *(const half8*)&phiF[base + 29 * CI];
            pv = hmax8(hmax8(p0, p1), hmax8(p2, p3));
            half8 g0 = *(const half8*)&gF[base];
            half8 g1 = *(const half8*)&gF[base + CI];
            half8 g2 = *(const half8*)&gF[base + 28 * CI];
            half8 g3 = *(const half8*)&gF[base + 29 * CI];
            gv = hmax8(hmax8(g0, g1), hmax8(g2, g3));
        } else {
#pragma unroll
            for (int j = 0; j < 8; j++) { pv[j] = (f16)0.f; gv[j] = (f16)0.f; }
        }
        *(half8*)&phiP[((size_t)b * MP + m) * CI + coff] = pv;
#pragma unroll
        for (int j = 0; j < 8; j++) gt[(coff + j) * 72 + ml] = gv[j];
    }
    __syncthreads();
#pragma unroll
    for (int i = 0; i < 4; i++) {
        int qq = tid + i * 256;
        int ci = qq >> 3, moff = (qq & 7) * 8;
        *(int4*)&gPT[((size_t)(b * CI) + ci) * MP + mt * 64 + moff] = *(const int4*)&gt[ci * 72 + moff];
    }
}

// ---------------- flash attention: y[b][n][ci] ----------------
// v5: swapped QK^T at 32x32x16 (S = mfma(K, Q) -> q cols lane-local), softmax + P fully
//     in registers (T12). 4 waves x 32 q, QBLK=128, grid (8, 49).
//     P->A repack: hi=0 lane needs m{0..7} = own a0,a1 + partner b0,b1;
//                  hi=1 lane needs m{8..15} = partner b2,b3 + own a2,a3.  (v4 had z/w swapped)
__global__ __launch_bounds__(256, 2) void k_attn(const f16* __restrict__ q,
                                                 const f16* __restrict__ kk,
                                                 const f16* __restrict__ v,
                                                 f16* __restrict__ y) {
    __shared__ f16 Ks[64 * 128];     // [64 m][128 d] linear, byte ^= ((row&15)<<4) swizzle
    __shared__ f16 Vs[128 * 72];     // [128 ci][64 m] pad 8
    int b = blockIdx.x, n0 = blockIdx.y * 128;
    int tid = threadIdx.x, w = tid >> 6, lane = tid & 63;
    int l31 = lane & 31, hi = lane >> 5;
    int wq = n0 + w * 32;

    // Q fragments (B-operand: col=lane&31=q, k=8*hi+j), pre-scaled by log2(e)
    half8 qf[8];
#pragma unroll
    for (int kc = 0; kc < 8; kc++) {
        qf[kc] = *(const half8*)&q[(size_t)(b * N + wq + l31) * CI + kc * 16 + hi * 8];
#pragma unroll
        for (int j = 0; j < 8; j++) qf[kc][j] *= (f16)1.4426950408889634f;
    }

    f32x16 O0, O1, O2, O3;
#pragma unroll
    for (int i = 0; i < 16; i++) { O0[i] = 0.f; O1[i] = 0.f; O2[i] = 0.f; O3[i] = 0.f; }
    float Osum = 0.f, mi = -1e30f;

    for (int mc = 0; mc < 25; mc++) {
        // ---- stage K (16KB, swizzled) + V (16KB) ----
#pragma unroll
        for (int i = 0; i < 4; i++) {
            int qq = tid + i * 256;
            int kr = qq >> 4, c16 = qq & 15;
            *(int4*)&Ks[kr * 128 + ((c16 ^ (kr & 15)) << 3)] =
                *(const int4*)&kk[((size_t)b * MP + mc * 64 + kr) * CI + c16 * 8];
            int vr = qq >> 3, vc = (qq & 7) * 8;
            *(int4*)&Vs[vr * 72 + vc] = *(const int4*)&v[((size_t)(b * CI) + vr) * MP + mc * 64 + vc];
        }
        __syncthreads();

        // ---- QK^T swapped: S[m][q], 16 MFMA32. A = K rows (lane&31 = m), B = Q regs ----
        f32x16 S0, S1;
#pragma unroll
        for (int i = 0; i < 16; i++) { S0[i] = 0.f; S1[i] = 0.f; }
        __builtin_amdgcn_s_setprio(1);
#pragma unroll
        for (int kc = 0; kc < 8; kc++) {
            int c16 = kc * 2 + hi;
            half8 a0 = *(const half8*)&Ks[l31 * 128 + ((c16 ^ (l31 & 15)) << 3)];
            half8 a1 = *(const half8*)&Ks[(32 + l31) * 128 + ((c16 ^ ((32 + l31) & 15)) << 3)];
            S0 = MFMA32(a0, qf[kc], S0);
            S1 = MFMA32(a1, qf[kc], S1);
        }
        __builtin_amdgcn_s_setprio(0);

        // ---- in-register online softmax (log2 domain). q = lane&31; m spread over regs+hi ----
        float vm = fmaxf(S0[0], S1[0]);
#pragma unroll
        for (int i = 1; i < 16; i++) vm = fmaxf(vm, fmaxf(S0[i], S1[i]));
        vm = fmaxf(vm, __shfl_xor(vm, 32));
        if (__ballot(vm > mi + 8.f)) {              // defer-rescale; wave-uniform
            float mnew = fmaxf(mi, vm);
            float alpha = __builtin_amdgcn_exp2f(mi - mnew);
            mi = mnew;
            Osum *= alpha;
#pragma unroll
            for (int r = 0; r < 16; r++) {          // alpha for O-row q_r via lane read
                int qr = (r & 3) + 8 * (r >> 2) + 4 * hi;
                float al = __shfl(alpha, qr);
                O0[r] *= al; O1[r] *= al; O2[r] *= al; O3[r] *= al;
            }
        }
#pragma unroll
        for (int i = 0; i < 16; i++) {
            S0[i] = __builtin_amdgcn_exp2f(S0[i] - mi);   // bounded by 2^8
            S1[i] = __builtin_amdgcn_exp2f(S1[i] - mi);
        }
        if (mc == 24) {                             // m 1568..1599 is zero-pad (mt==1 half)
#pragma unroll
            for (int i = 0; i < 16; i++) S1[i] = 0.f;
        }
        float ts = 0.f;
#pragma unroll
        for (int i = 0; i < 16; i++) ts += S0[i] + S1[i];
        ts += __shfl_xor(ts, 32);
        Osum += ts;

        // ---- P -> A-fragments (cvt_pk + half-swap + select), PV: 16 MFMA32 ----
        __builtin_amdgcn_s_setprio(1);
#define PV_CHUNK(SV, RB, KC)                                                              \
        {                                                                                 \
            int a0 = pk2(SV[RB + 0], SV[RB + 1]);                                         \
            int a1 = pk2(SV[RB + 2], SV[RB + 3]);                                         \
            int a2 = pk2(SV[RB + 4], SV[RB + 5]);                                         \
            int a3 = pk2(SV[RB + 6], SV[RB + 7]);                                         \
            int b0 = __shfl_xor(a0, 32), b1 = __shfl_xor(a1, 32);                         \
            int b2 = __shfl_xor(a2, 32), b3 = __shfl_xor(a3, 32);                         \
            union { int4 i4; half8 h8; } u;                                               \
            u.i4.x = hi ? b2 : a0; u.i4.y = hi ? b3 : a1;                                 \
            u.i4.z = hi ? a2 : b0; u.i4.w = hi ? a3 : b1;                                 \
            O0 = MFMA32(u.h8, *(const half8*)&Vs[(0 * 32 + l31) * 72 + KC * 16 + hi * 8], O0); \
            O1 = MFMA32(u.h8, *(const half8*)&Vs[(1 * 32 + l31) * 72 + KC * 16 + hi * 8], O1); \
            O2 = MFMA32(u.h8, *(const half8*)&Vs[(2 * 32 + l31) * 72 + KC * 16 + hi * 8], O2); \
            O3 = MFMA32(u.h8, *(const half8*)&Vs[(3 * 32 + l31) * 72 + KC * 16 + hi * 8], O3); \
        }
        PV_CHUNK(S0, 0, 0)
        PV_CHUNK(S0, 8, 1)
        PV_CHUNK(S1, 0, 2)
        PV_CHUNK(S1, 8, 3)
#undef PV_CHUNK
        __builtin_amdgcn_s_setprio(0);
        __syncthreads();
    }

    // ---- epilogue: y[q][ci] = O / Osum(q). O row q_r = (r&3)+8*(r>>2)+4*hi, col = lane&31 ----
#pragma unroll
    for (int r = 0; r < 16; r++) {
        int qr = (r & 3) + 8 * (r >> 2) + 4 * hi;
        float inv = 1.0f / __shfl(Osum, qr);
        size_t base = (size_t)(b * N + wq + qr) * CI + l31;
        y[base]      = (f16)(O0[r] * inv);
        y[base + 32] = (f16)(O1[r] * inv);
        y[base + 64] = (f16)(O2[r] * inv);
        y[base + 96] = (f16)(O3[r] * inv);
    }
}

// ---------------- final: out[b][c][n] = W.y + Wb + x ----------------
// grid (8, 98, 2): b = blockIdx.x, n-tile = blockIdx.y, c-half = blockIdx.z
__global__ __launch_bounds__(256) void k_final(const f16* __restrict__ y,
                                               const f16* __restrict__ Ww,
                                               const float* __restrict__ Wb,
                                               const float* __restrict__ x,
                                               float* __restrict__ out) {
    __shared__ f16 ys[64 * 136];    // [64 n][128 ci] pad 8
    __shared__ f16 Ws[128 * 136];   // [128 c][128 ci] pad 8
    int b = blockIdx.x, ch = blockIdx.z, n0 = blockIdx.y * 64;
    int tid = threadIdx.x, w = tid >> 6, lane = tid & 63, ln = lane & 15, quad = lane >> 4;
#pragma unroll
    for (int i = 0; i < 4; i++) {
        int qq = tid + i * 256; int row = qq >> 4, coff = (qq & 15) * 8;
        *(int4*)&ys[row * 136 + coff] =
            *(const int4*)&y[(size_t)(b * N + n0 + row) * CI + coff];
    }
#pragma unroll
    for (int i = 0; i < 8; i++) {
        int qq = tid + i * 256; int row = qq >> 4, coff = (qq & 15) * 8;
        *(int4*)&Ws[row * 136 + coff] =
            *(const int4*)&Ww[(size_t)(ch * 128 + row) * CI + coff];
    }
    __syncthreads();
    f32x4 acc[2][4];
#pragma unroll
    for (int rb = 0; rb < 2; rb++)
#pragma unroll
        for (int nb = 0; nb < 4; nb++) acc[rb][nb] = (f32x4){0.f, 0.f, 0.f, 0.f};
#pragma unroll
    for (int ks = 0; ks < 4; ks++) {
        half8 a0 = *(const half8*)&Ws[(w * 32 + ln) * 136 + ks * 32 + quad * 8];
        half8 a1 = *(const half8*)&Ws[(w * 32 + 16 + ln) * 136 + ks * 32 + quad * 8];
#pragma unroll
        for (int nb = 0; nb < 4; nb++) {
            half8 bf = *(const half8*)&ys[(nb * 16 + ln) * 136 + ks * 32 + quad * 8];
            acc[0][nb] = MFMA16(a0, bf, acc[0][nb]);
            acc[1][nb] = MFMA16(a1, bf, acc[1][nb]);
        }
    }
#pragma unroll
    for (int rb = 0; rb < 2; rb++) {
        int cbase = ch * 128 + w * 32 + rb * 16 + quad * 4;
#pragma unroll
        for (int nb = 0; nb < 4; nb++) {
#pragma unroll
            for (int r = 0; r < 4; r++) {
                int c = cbase + r;
                size_t addr = (size_t)(b * C + c) * N + n0 + nb * 16 + ln;
                out[addr] = acc[rb][nb][r] + Wb[c] + x[addr];
            }
        }
    }
}

extern "C" void kernel_launch(void* const* d_in, const int* in_sizes, int n_in,
                              void* d_out, int out_size, void* d_ws, size_t ws_size,
                              hipStream_t stream) {
    const float* x  = (const float*)d_in[0];
    const float* gw = (const float*)d_in[1];
    const float* gb = (const float*)d_in[2];
    const float* tw = (const float*)d_in[3];
    const float* tb = (const float*)d_in[4];
    const float* pw = (const float*)d_in[5];
    const float* pb = (const float*)d_in[6];
    const float* Ww = (const float*)d_in[7];
    const float* Wb = (const float*)d_in[8];
    float* out = (float*)d_out;
    f16* ws = (f16*)d_ws;

    f16* xT   = ws + oXT;
    f16* Q    = ws + oQ;
    f16* phiF = ws + oPF;
    f16* gF   = ws + oGF;
    f16* phiP = ws + oPP;
    f16* gPT  = ws + oGT;
    f16* Y    = ws + oPF;   // alias: phiF dead after k_pool
    f16* w16  = ws + oW;

    k_prep<<<512, 256, 0, stream>>>(tw, pw, gw, Ww, w16);
    k_trans<<<dim3(8, 196, 8), dim3(32, 8), 0, stream>>>(x, xT);
    k_proj<<<dim3(8, 49), 256, 0, stream>>>(xT, w16,         tb, Q);
    k_proj<<<dim3(8, 49), 256, 0, stream>>>(xT, w16 + 32768, pb, phiF);
    k_proj<<<dim3(8, 49), 256, 0, stream>>>(xT, w16 + 65536, gb, gF);
    k_pool<<<dim3(8, 25), 256, 0, stream>>>(phiF, gF, phiP, gPT);
    k_attn<<<dim3(8, 49), 256, 0, stream>>>(Q, phiP, gPT, Y);
    k_final<<<dim3(8, 98, 2), 256, 0, stream>>>(Y, w16 + 98304, Wb, x, out);
    (void)in_sizes; (void)n_in; (void)out_size; (void)ws_size;
}

// Round 6
// 234.133 us; speedup vs baseline: 1.8037x; 1.0829x over previous
//
#include <hip/hip_runtime.h>

typedef _Float16 f16;
typedef f16 half8 __attribute__((ext_vector_type(8)));
typedef __fp16 fp16x2 __attribute__((ext_vector_type(2)));
typedef float f32x4 __attribute__((ext_vector_type(4)));
typedef float f32x16 __attribute__((ext_vector_type(16)));

#define MFMA16(a, b, c) __builtin_amdgcn_mfma_f32_16x16x32_f16((a), (b), (c), 0, 0, 0)
#define MFMA32(a, b, c) __builtin_amdgcn_mfma_f32_32x32x16_f16((a), (b), (c), 0, 0, 0)

static constexpr int B = 8, C = 256, CI = 128, N = 6272, M = 1568, MP = 1600;

// f16-element offsets into workspace (~71 MB). Y aliases phiF (consumed by k_pool).
static constexpr size_t oXT = 0;                         // [B][N][C]   x transposed, f16
static constexpr size_t oQ  = (size_t)B * N * C;         // [B][N][CI]  theta (log2e folded at attn load)
static constexpr size_t oPF = oQ  + (size_t)B * N * CI;  // [B][N][CI]  phi full-res; later Y
static constexpr size_t oGF = oPF + (size_t)B * N * CI;  // [B][N][CI]  g full-res
static constexpr size_t oPP = oGF + (size_t)B * N * CI;  // [B][MP][CI] phi pooled (K), pad zeroed
static constexpr size_t oGT = oPP + (size_t)B * MP * CI; // [B][CI][MP] g pooled transposed (V), pad zeroed
static constexpr size_t oW  = oGT + (size_t)B * MP * CI; // 4*32768 f16 weights: theta|phi|g|W

static __device__ __forceinline__ half8 hmax8(half8 a, half8 b) {
    half8 r;
#pragma unroll
    for (int j = 0; j < 8; j++) r[j] = a[j] > b[j] ? a[j] : b[j];
    return r;
}

static __device__ __forceinline__ int pk2(float a, float b) {
    union { fp16x2 h; int i; } u;
    u.h = __builtin_amdgcn_cvt_pkrtz(a, b);
    return u.i;
}

// ---------------- weight cast fp32 -> f16 ----------------
__global__ void k_prep(const float* tw, const float* pw, const float* gw,
                       const float* Ww, f16* dst) {
    int i = blockIdx.x * 256 + threadIdx.x;   // 0..131071
    int s = i >> 15, j = i & 32767;
    float v;
    if (s == 0) v = tw[j];
    else if (s == 1) v = pw[j];
    else if (s == 2) v = gw[j];
    else v = Ww[j];
    dst[i] = (f16)v;
}

// ---------------- x[b][c][n] fp32 -> xT[b][n][c] f16 ----------------
// grid (8, 196, 8): b in blockIdx.x so batch b lands on XCD b (round-robin by linear id)
__global__ void k_trans(const float* x, f16* xT) {
    __shared__ float tile[32][33];
    int b = blockIdx.x, nt = blockIdx.y, ct = blockIdx.z;
    int tx = threadIdx.x, ty = threadIdx.y;
#pragma unroll
    for (int i = 0; i < 4; i++) {
        int c = ct * 32 + ty + i * 8;
        tile[ty + i * 8][tx] = x[(size_t)(b * C + c) * N + nt * 32 + tx];
    }
    __syncthreads();
#pragma unroll
    for (int i = 0; i < 4; i++) {
        int n = nt * 32 + ty + i * 8;
        xT[(size_t)(b * N + n) * C + ct * 32 + tx] = (f16)tile[tx][ty + i * 8];
    }
}

// ---------------- fused projection GEMM: {theta,phi,g}[b][n][ci] = xT[b][n][:] . w_p + bias_p ----
// One pass over xT instead of three. grid (8, 98): b = blockIdx.x, 64-row n-tile = blockIdx.y.
// 4 waves x 16 rows; acc[3][8] f32x4 = 96 VGPR; LDS 63KB -> 2 blocks/CU.
__global__ __launch_bounds__(256, 2) void k_proj3(const f16* __restrict__ xT,
                                                  const f16* __restrict__ w16,
                                                  const float* __restrict__ tb,
                                                  const float* __restrict__ pb,
                                                  const float* __restrict__ gb,
                                                  f16* __restrict__ outQ,
                                                  f16* __restrict__ outP,
                                                  f16* __restrict__ outG) {
    __shared__ f16 xs[64 * 72];        // [64 n][64 k] pad 8
    __shared__ f16 ws[3 * 128 * 72];   // per proj: [128 ci][64 k] pad 8
    int b = blockIdx.x, n0 = blockIdx.y * 64;
    int tid = threadIdx.x, w = tid >> 6, lane = tid & 63, ln = lane & 15, quad = lane >> 4;
    f32x4 acc[3][8];
#pragma unroll
    for (int p = 0; p < 3; p++)
#pragma unroll
        for (int cb = 0; cb < 8; cb++) acc[p][cb] = (f32x4){0.f, 0.f, 0.f, 0.f};

    for (int kc = 0; kc < 4; kc++) {
        // stage xs: 64x64 f16 = 512 int4 tasks
#pragma unroll
        for (int i = 0; i < 2; i++) {
            int qq = tid + i * 256;            // 0..511
            int row = qq >> 3, coff = (qq & 7) * 8;
            *(int4*)&xs[row * 72 + coff] =
                *(const int4*)&xT[(size_t)(b * N + n0 + row) * C + kc * 64 + coff];
        }
        // stage ws: 3 x 128x64 f16 = 3072 int4 tasks (L2-resident after first block)
#pragma unroll
        for (int p = 0; p < 3; p++)
#pragma unroll
            for (int i = 0; i < 4; i++) {
                int qq = tid + i * 256;        // 0..1023
                int row = qq >> 3, coff = (qq & 7) * 8;
                *(int4*)&ws[p * 9216 + row * 72 + coff] =
                    *(const int4*)&w16[(size_t)p * 32768 + (size_t)row * C + kc * 64 + coff];
            }
        __syncthreads();
#pragma unroll
        for (int ks = 0; ks < 2; ks++) {
            half8 a = *(const half8*)&xs[(w * 16 + ln) * 72 + ks * 32 + quad * 8];
#pragma unroll
            for (int p = 0; p < 3; p++)
#pragma unroll
                for (int cb = 0; cb < 8; cb++) {
                    half8 bf = *(const half8*)&ws[p * 9216 + (cb * 16 + ln) * 72 + ks * 32 + quad * 8];
                    acc[p][cb] = MFMA16(a, bf, acc[p][cb]);
                }
        }
        __syncthreads();
    }
#pragma unroll
    for (int p = 0; p < 3; p++) {
        const float* bias = (p == 0) ? tb : (p == 1) ? pb : gb;
        f16* out = (p == 0) ? outQ : (p == 1) ? outP : outG;
#pragma unroll
        for (int cb = 0; cb < 8; cb++) {
            float bv = bias[cb * 16 + ln];
#pragma unroll
            for (int r = 0; r < 4; r++) {
                int n = n0 + w * 16 + quad * 4 + r;
                out[(size_t)(b * N + n) * CI + cb * 16 + ln] = (f16)(acc[p][cb][r] + bv);
            }
        }
    }
}

// ---------------- 2x2 spatial maxpool; K as [m][ci], V as [ci][m] (coalesced via LDS transpose) ----
// grid (8, 25): b = blockIdx.x
__global__ __launch_bounds__(256) void k_pool(const f16* __restrict__ phiF, const f16* __restrict__ gF,
                                              f16* __restrict__ phiP, f16* __restrict__ gPT) {
    __shared__ f16 gt[128 * 72];   // [128 ci][64 m] pad 8
    int b = blockIdx.x, mt = blockIdx.y;   // mt 0..24 over MP=1600
    int tid = threadIdx.x;
#pragma unroll
    for (int i = 0; i < 4; i++) {
        int qq = tid + i * 256;            // 0..1023
        int ml = qq >> 4, coff = (qq & 15) * 8;
        int m = mt * 64 + ml;
        half8 pv, gv;
        if (m < M) {
            int t = m / 196, rr = m % 196, hp = rr / 14, wp = rr % 14;
            int nb = t * 784 + hp * 56 + wp * 2;
            size_t base = ((size_t)(b * N) + nb) * CI + coff;
            half8 p0 = *(const half8*)&phiF[base];
            half8 p1 = *(const half8*)&phiF[base + CI];
            half8 p2 = *(const half8*)&phiF[base + 28 * CI];
            half8 p3 = *(const half8*)&phiF[base + 29 * CI];
            pv = hmax8(hmax8(p0, p1), hmax8(p2, p3));
            half8 g0 = *(const half8*)&gF[base];
            half8 g1 = *(const half8*)&gF[base + CI];
            half8 g2 = *(const half8*)&gF[base + 28 * CI];
            half8 g3 = *(const half8*)&gF[base + 29 * CI];
            gv = hmax8(hmax8(g0, g1), hmax8(g2, g3));
        } else {
#pragma unroll
            for (int j = 0; j < 8; j++) { pv[j] = (f16)0.f; gv[j] = (f16)0.f; }
        }
        *(half8*)&phiP[((size_t)b * MP + m) * CI + coff] = pv;
#pragma unroll
        for (int j = 0; j < 8; j++) gt[(coff + j) * 72 + ml] = gv[j];
    }
    __syncthreads();
#pragma unroll
    for (int i = 0; i < 4; i++) {
        int qq = tid + i * 256;
        int ci = qq >> 3, moff = (qq & 7) * 8;
        *(int4*)&gPT[((size_t)(b * CI) + ci) * MP + mt * 64 + moff] = *(const int4*)&gt[ci * 72 + moff];
    }
}

// ---------------- flash attention: y[b][n][ci] ----------------
// v5: swapped QK^T at 32x32x16 (S = mfma(K, Q) -> q cols lane-local), softmax + P fully
//     in registers (T12). 4 waves x 32 q, QBLK=128, grid (8, 49).
//     P->A repack: hi=0 lane needs m{0..7} = own a0,a1 + partner b0,b1;
//                  hi=1 lane needs m{8..15} = partner b2,b3 + own a2,a3.
__global__ __launch_bounds__(256, 2) void k_attn(const f16* __restrict__ q,
                                                 const f16* __restrict__ kk,
                                                 const f16* __restrict__ v,
                                                 f16* __restrict__ y) {
    __shared__ f16 Ks[64 * 128];     // [64 m][128 d] linear, byte ^= ((row&15)<<4) swizzle
    __shared__ f16 Vs[128 * 72];     // [128 ci][64 m] pad 8
    int b = blockIdx.x, n0 = blockIdx.y * 128;
    int tid = threadIdx.x, w = tid >> 6, lane = tid & 63;
    int l31 = lane & 31, hi = lane >> 5;
    int wq = n0 + w * 32;

    // Q fragments (B-operand: col=lane&31=q, k=8*hi+j), pre-scaled by log2(e)
    half8 qf[8];
#pragma unroll
    for (int kc = 0; kc < 8; kc++) {
        qf[kc] = *(const half8*)&q[(size_t)(b * N + wq + l31) * CI + kc * 16 + hi * 8];
#pragma unroll
        for (int j = 0; j < 8; j++) qf[kc][j] *= (f16)1.4426950408889634f;
    }

    f32x16 O0, O1, O2, O3;
#pragma unroll
    for (int i = 0; i < 16; i++) { O0[i] = 0.f; O1[i] = 0.f; O2[i] = 0.f; O3[i] = 0.f; }
    float Osum = 0.f, mi = -1e30f;

    for (int mc = 0; mc < 25; mc++) {
        // ---- stage K (16KB, swizzled) + V (16KB) ----
#pragma unroll
        for (int i = 0; i < 4; i++) {
            int qq = tid + i * 256;
            int kr = qq >> 4, c16 = qq & 15;
            *(int4*)&Ks[kr * 128 + ((c16 ^ (kr & 15)) << 3)] =
                *(const int4*)&kk[((size_t)b * MP + mc * 64 + kr) * CI + c16 * 8];
            int vr = qq >> 3, vc = (qq & 7) * 8;
            *(int4*)&Vs[vr * 72 + vc] = *(const int4*)&v[((size_t)(b * CI) + vr) * MP + mc * 64 + vc];
        }
        __syncthreads();

        // ---- QK^T swapped: S[m][q], 16 MFMA32. A = K rows (lane&31 = m), B = Q regs ----
        f32x16 S0, S1;
#pragma unroll
        for (int i = 0; i < 16; i++) { S0[i] = 0.f; S1[i] = 0.f; }
        __builtin_amdgcn_s_setprio(1);
#pragma unroll
        for (int kc = 0; kc < 8; kc++) {
            int c16 = kc * 2 + hi;
            half8 a0 = *(const half8*)&Ks[l31 * 128 + ((c16 ^ (l31 & 15)) << 3)];
            half8 a1 = *(const half8*)&Ks[(32 + l31) * 128 + ((c16 ^ ((32 + l31) & 15)) << 3)];
            S0 = MFMA32(a0, qf[kc], S0);
            S1 = MFMA32(a1, qf[kc], S1);
        }
        __builtin_amdgcn_s_setprio(0);

        // ---- in-register online softmax (log2 domain). q = lane&31; m spread over regs+hi ----
        float vm = fmaxf(S0[0], S1[0]);
#pragma unroll
        for (int i = 1; i < 16; i++) vm = fmaxf(vm, fmaxf(S0[i], S1[i]));
        vm = fmaxf(vm, __shfl_xor(vm, 32));
        if (__ballot(vm > mi + 8.f)) {              // defer-rescale; wave-uniform
            float mnew = fmaxf(mi, vm);
            float alpha = __builtin_amdgcn_exp2f(mi - mnew);
            mi = mnew;
            Osum *= alpha;
#pragma unroll
            for (int r = 0; r < 16; r++) {          // alpha for O-row q_r via lane read
                int qr = (r & 3) + 8 * (r >> 2) + 4 * hi;
                float al = __shfl(alpha, qr);
                O0[r] *= al; O1[r] *= al; O2[r] *= al; O3[r] *= al;
            }
        }
#pragma unroll
        for (int i = 0; i < 16; i++) {
            S0[i] = __builtin_amdgcn_exp2f(S0[i] - mi);   // bounded by 2^8
            S1[i] = __builtin_amdgcn_exp2f(S1[i] - mi);
        }
        if (mc == 24) {                             // m 1568..1599 is zero-pad (mt==1 half)
#pragma unroll
            for (int i = 0; i < 16; i++) S1[i] = 0.f;
        }
        float ts = 0.f;
#pragma unroll
        for (int i = 0; i < 16; i++) ts += S0[i] + S1[i];
        ts += __shfl_xor(ts, 32);
        Osum += ts;

        // ---- P -> A-fragments (cvt_pk + half-swap + select), PV: 16 MFMA32 ----
        __builtin_amdgcn_s_setprio(1);
#define PV_CHUNK(SV, RB, KC)                                                              \
        {                                                                                 \
            int a0 = pk2(SV[RB + 0], SV[RB + 1]);                                         \
            int a1 = pk2(SV[RB + 2], SV[RB + 3]);                                         \
            int a2 = pk2(SV[RB + 4], SV[RB + 5]);                                         \
            int a3 = pk2(SV[RB + 6], SV[RB + 7]);                                         \
            int b0 = __shfl_xor(a0, 32), b1 = __shfl_xor(a1, 32);                         \
            int b2 = __shfl_xor(a2, 32), b3 = __shfl_xor(a3, 32);                         \
            union { int4 i4; half8 h8; } u;                                               \
            u.i4.x = hi ? b2 : a0; u.i4.y = hi ? b3 : a1;                                 \
            u.i4.z = hi ? a2 : b0; u.i4.w = hi ? a3 : b1;                                 \
            O0 = MFMA32(u.h8, *(const half8*)&Vs[(0 * 32 + l31) * 72 + KC * 16 + hi * 8], O0); \
            O1 = MFMA32(u.h8, *(const half8*)&Vs[(1 * 32 + l31) * 72 + KC * 16 + hi * 8], O1); \
            O2 = MFMA32(u.h8, *(const half8*)&Vs[(2 * 32 + l31) * 72 + KC * 16 + hi * 8], O2); \
            O3 = MFMA32(u.h8, *(const half8*)&Vs[(3 * 32 + l31) * 72 + KC * 16 + hi * 8], O3); \
        }
        PV_CHUNK(S0, 0, 0)
        PV_CHUNK(S0, 8, 1)
        PV_CHUNK(S1, 0, 2)
        PV_CHUNK(S1, 8, 3)
#undef PV_CHUNK
        __builtin_amdgcn_s_setprio(0);
        __syncthreads();
    }

    // ---- epilogue: y[q][ci] = O / Osum(q). O row q_r = (r&3)+8*(r>>2)+4*hi, col = lane&31 ----
#pragma unroll
    for (int r = 0; r < 16; r++) {
        int qr = (r & 3) + 8 * (r >> 2) + 4 * hi;
        float inv = 1.0f / __shfl(Osum, qr);
        size_t base = (size_t)(b * N + wq + qr) * CI + l31;
        y[base]      = (f16)(O0[r] * inv);
        y[base + 32] = (f16)(O1[r] * inv);
        y[base + 64] = (f16)(O2[r] * inv);
        y[base + 96] = (f16)(O3[r] * inv);
    }
}

// ---------------- final: out[b][c][n] = W.y + Wb + x ----------------
// grid (8, 98, 2): b = blockIdx.x, n-tile = blockIdx.y, c-half = blockIdx.z
__global__ __launch_bounds__(256) void k_final(const f16* __restrict__ y,
                                               const f16* __restrict__ Ww,
                                               const float* __restrict__ Wb,
                                               const float* __restrict__ x,
                                               float* __restrict__ out) {
    __shared__ f16 ys[64 * 136];    // [64 n][128 ci] pad 8
    __shared__ f16 Ws[128 * 136];   // [128 c][128 ci] pad 8
    int b = blockIdx.x, ch = blockIdx.z, n0 = blockIdx.y * 64;
    int tid = threadIdx.x, w = tid >> 6, lane = tid & 63, ln = lane & 15, quad = lane >> 4;
#pragma unroll
    for (int i = 0; i < 4; i++) {
        int qq = tid + i * 256; int row = qq >> 4, coff = (qq & 15) * 8;
        *(int4*)&ys[row * 136 + coff] =
            *(const int4*)&y[(size_t)(b * N + n0 + row) * CI + coff];
    }
#pragma unroll
    for (int i = 0; i < 8; i++) {
        int qq = tid + i * 256; int row = qq >> 4, coff = (qq & 15) * 8;
        *(int4*)&Ws[row * 136 + coff] =
            *(const int4*)&Ww[(size_t)(ch * 128 + row) * CI + coff];
    }
    __syncthreads();
    f32x4 acc[2][4];
#pragma unroll
    for (int rb = 0; rb < 2; rb++)
#pragma unroll
        for (int nb = 0; nb < 4; nb++) acc[rb][nb] = (f32x4){0.f, 0.f, 0.f, 0.f};
#pragma unroll
    for (int ks = 0; ks < 4; ks++) {
        half8 a0 = *(const half8*)&Ws[(w * 32 + ln) * 136 + ks * 32 + quad * 8];
        half8 a1 = *(const half8*)&Ws[(w * 32 + 16 + ln) * 136 + ks * 32 + quad * 8];
#pragma unroll
        for (int nb = 0; nb < 4; nb++) {
            half8 bf = *(const half8*)&ys[(nb * 16 + ln) * 136 + ks * 32 + quad * 8];
            acc[0][nb] = MFMA16(a0, bf, acc[0][nb]);
            acc[1][nb] = MFMA16(a1, bf, acc[1][nb]);
        }
    }
#pragma unroll
    for (int rb = 0; rb < 2; rb++) {
        int cbase = ch * 128 + w * 32 + rb * 16 + quad * 4;
#pragma unroll
        for (int nb = 0; nb < 4; nb++) {
#pragma unroll
            for (int r = 0; r < 4; r++) {
                int c = cbase + r;
                size_t addr = (size_t)(b * C + c) * N + n0 + nb * 16 + ln;
                out[addr] = acc[rb][nb][r] + Wb[c] + x[addr];
            }
        }
    }
}

extern "C" void kernel_launch(void* const* d_in, const int* in_sizes, int n_in,
                              void* d_out, int out_size, void* d_ws, size_t ws_size,
                              hipStream_t stream) {
    const float* x  = (const float*)d_in[0];
    const float* gw = (const float*)d_in[1];
    const float* gb = (const float*)d_in[2];
    const float* tw = (const float*)d_in[3];
    const float* tb = (const float*)d_in[4];
    const float* pw = (const float*)d_in[5];
    const float* pb = (const float*)d_in[6];
    const float* Ww = (const float*)d_in[7];
    const float* Wb = (const float*)d_in[8];
    float* out = (float*)d_out;
    f16* ws = (f16*)d_ws;

    f16* xT   = ws + oXT;
    f16* Q    = ws + oQ;
    f16* phiF = ws + oPF;
    f16* gF   = ws + oGF;
    f16* phiP = ws + oPP;
    f16* gPT  = ws + oGT;
    f16* Y    = ws + oPF;   // alias: phiF dead after k_pool
    f16* w16  = ws + oW;

    k_prep<<<512, 256, 0, stream>>>(tw, pw, gw, Ww, w16);
    k_trans<<<dim3(8, 196, 8), dim3(32, 8), 0, stream>>>(x, xT);
    k_proj3<<<dim3(8, 98), 256, 0, stream>>>(xT, w16, tb, pb, gb, Q, phiF, gF);
    k_pool<<<dim3(8, 25), 256, 0, stream>>>(phiF, gF, phiP, gPT);
    k_attn<<<dim3(8, 49), 256, 0, stream>>>(Q, phiP, gPT, Y);
    k_final<<<dim3(8, 98, 2), 256, 0, stream>>>(Y, w16 + 98304, Wb, x, out);
    (void)in_sizes; (void)n_in; (void)out_size; (void)ws_size;
}

// Round 7
// 229.389 us; speedup vs baseline: 1.8411x; 1.0207x over previous
//
#include <hip/hip_runtime.h>

typedef _Float16 f16;
typedef f16 half8 __attribute__((ext_vector_type(8)));
typedef __fp16 fp16x2 __attribute__((ext_vector_type(2)));
typedef float f32x4 __attribute__((ext_vector_type(4)));
typedef float f32x16 __attribute__((ext_vector_type(16)));

#define MFMA16(a, b, c) __builtin_amdgcn_mfma_f32_16x16x32_f16((a), (b), (c), 0, 0, 0)
#define MFMA32(a, b, c) __builtin_amdgcn_mfma_f32_32x32x16_f16((a), (b), (c), 0, 0, 0)

static constexpr int B = 8, C = 256, CI = 128, N = 6272, M = 1568, MP = 1600;

// f16-element offsets into workspace (~71 MB). Y aliases phiF (consumed by k_pool).
// oXT slot retained (unused since the transpose was fused into k_proj3).
static constexpr size_t oXT = 0;                         // [B][N][C]   (unused)
static constexpr size_t oQ  = (size_t)B * N * C;         // [B][N][CI]  theta (log2e folded at attn load)
static constexpr size_t oPF = oQ  + (size_t)B * N * CI;  // [B][N][CI]  phi full-res; later Y
static constexpr size_t oGF = oPF + (size_t)B * N * CI;  // [B][N][CI]  g full-res
static constexpr size_t oPP = oGF + (size_t)B * N * CI;  // [B][MP][CI] phi pooled (K), pad zeroed
static constexpr size_t oGT = oPP + (size_t)B * MP * CI; // [B][CI][MP] g pooled transposed (V), pad zeroed
static constexpr size_t oW  = oGT + (size_t)B * MP * CI; // 4*32768 f16 weights: theta|phi|g|W

static __device__ __forceinline__ half8 hmax8(half8 a, half8 b) {
    half8 r;
#pragma unroll
    for (int j = 0; j < 8; j++) r[j] = a[j] > b[j] ? a[j] : b[j];
    return r;
}

static __device__ __forceinline__ int pk2(float a, float b) {
    union { fp16x2 h; int i; } u;
    u.h = __builtin_amdgcn_cvt_pkrtz(a, b);
    return u.i;
}

// ---------------- weight cast fp32 -> f16 ----------------
__global__ void k_prep(const float* tw, const float* pw, const float* gw,
                       const float* Ww, f16* dst) {
    int i = blockIdx.x * 256 + threadIdx.x;   // 0..131071
    int s = i >> 15, j = i & 32767;
    float v;
    if (s == 0) v = tw[j];
    else if (s == 1) v = pw[j];
    else if (s == 2) v = gw[j];
    else v = Ww[j];
    dst[i] = (f16)v;
}

// ---------------- fused transpose + projection GEMM ----------------
// {theta,phi,g}[b][n][ci] = x[b][:][n] . w_p + bias_p.  Transpose folded into staging:
// x is read in native [c][n] layout (64 consecutive n per c-row = coalesced 256B/wave),
// cast to f16, scattered into xs[n][c].  Kills the separate k_trans kernel + xT round-trip.
// grid (8, 98): b = blockIdx.x, 64-row n-tile = blockIdx.y.  4 waves x 16 rows.
__global__ __launch_bounds__(256, 2) void k_proj3(const float* __restrict__ x,
                                                  const f16* __restrict__ w16,
                                                  const float* __restrict__ tb,
                                                  const float* __restrict__ pb,
                                                  const float* __restrict__ gb,
                                                  f16* __restrict__ outQ,
                                                  f16* __restrict__ outP,
                                                  f16* __restrict__ outG) {
    __shared__ f16 xs[64 * 72];        // [64 n][64 k] pad 8
    __shared__ f16 ws[3 * 128 * 72];   // per proj: [128 ci][64 k] pad 8
    int b = blockIdx.x, n0 = blockIdx.y * 64;
    int tid = threadIdx.x, w = tid >> 6, lane = tid & 63, ln = lane & 15, quad = lane >> 4;
    f32x4 acc[3][8];
#pragma unroll
    for (int p = 0; p < 3; p++)
#pragma unroll
        for (int cb = 0; cb < 8; cb++) acc[p][cb] = (f32x4){0.f, 0.f, 0.f, 0.f};

    for (int kc = 0; kc < 4; kc++) {
        // stage xs with in-flight transpose: 4096 scalar tasks (16/thread), reads coalesced
#pragma unroll
        for (int i = 0; i < 16; i++) {
            int qq = tid + i * 256;            // 0..4095
            int nn = qq & 63, cc = qq >> 6;    // lanes -> consecutive n (coalesced)
            float v = x[(size_t)(b * C + kc * 64 + cc) * N + n0 + nn];
            xs[nn * 72 + cc] = (f16)v;
        }
        // stage ws: 3 x 128x64 f16 (L2-resident after first block)
#pragma unroll
        for (int p = 0; p < 3; p++)
#pragma unroll
            for (int i = 0; i < 4; i++) {
                int qq = tid + i * 256;        // 0..1023
                int row = qq >> 3, coff = (qq & 7) * 8;
                *(int4*)&ws[p * 9216 + row * 72 + coff] =
                    *(const int4*)&w16[(size_t)p * 32768 + (size_t)row * C + kc * 64 + coff];
            }
        __syncthreads();
#pragma unroll
        for (int ks = 0; ks < 2; ks++) {
            half8 a = *(const half8*)&xs[(w * 16 + ln) * 72 + ks * 32 + quad * 8];
#pragma unroll
            for (int p = 0; p < 3; p++)
#pragma unroll
                for (int cb = 0; cb < 8; cb++) {
                    half8 bf = *(const half8*)&ws[p * 9216 + (cb * 16 + ln) * 72 + ks * 32 + quad * 8];
                    acc[p][cb] = MFMA16(a, bf, acc[p][cb]);
                }
        }
        __syncthreads();
    }
#pragma unroll
    for (int p = 0; p < 3; p++) {
        const float* bias = (p == 0) ? tb : (p == 1) ? pb : gb;
        f16* out = (p == 0) ? outQ : (p == 1) ? outP : outG;
#pragma unroll
        for (int cb = 0; cb < 8; cb++) {
            float bv = bias[cb * 16 + ln];
#pragma unroll
            for (int r = 0; r < 4; r++) {
                int n = n0 + w * 16 + quad * 4 + r;
                out[(size_t)(b * N + n) * CI + cb * 16 + ln] = (f16)(acc[p][cb][r] + bv);
            }
        }
    }
}

// ---------------- 2x2 spatial maxpool; K as [m][ci], V as [ci][m] (coalesced via LDS transpose) ----
// grid (8, 25): b = blockIdx.x
__global__ __launch_bounds__(256) void k_pool(const f16* __restrict__ phiF, const f16* __restrict__ gF,
                                              f16* __restrict__ phiP, f16* __restrict__ gPT) {
    __shared__ f16 gt[128 * 72];   // [128 ci][64 m] pad 8
    int b = blockIdx.x, mt = blockIdx.y;   // mt 0..24 over MP=1600
    int tid = threadIdx.x;
#pragma unroll
    for (int i = 0; i < 4; i++) {
        int qq = tid + i * 256;            // 0..1023
        int ml = qq >> 4, coff = (qq & 15) * 8;
        int m = mt * 64 + ml;
        half8 pv, gv;
        if (m < M) {
            int t = m / 196, rr = m % 196, hp = rr / 14, wp = rr % 14;
            int nb = t * 784 + hp * 56 + wp * 2;
            size_t base = ((size_t)(b * N) + nb) * CI + coff;
            half8 p0 = *(const half8*)&phiF[base];
            half8 p1 = *(const half8*)&phiF[base + CI];
            half8 p2 = *(const half8*)&phiF[base + 28 * CI];
            half8 p3 = *(const half8*)&phiF[base + 29 * CI];
            pv = hmax8(hmax8(p0, p1), hmax8(p2, p3));
            half8 g0 = *(const half8*)&gF[base];
            half8 g1 = *(const half8*)&gF[base + CI];
            half8 g2 = *(const half8*)&gF[base + 28 * CI];
            half8 g3 = *(const half8*)&gF[base + 29 * CI];
            gv = hmax8(hmax8(g0, g1), hmax8(g2, g3));
        } else {
#pragma unroll
            for (int j = 0; j < 8; j++) { pv[j] = (f16)0.f; gv[j] = (f16)0.f; }
        }
        *(half8*)&phiP[((size_t)b * MP + m) * CI + coff] = pv;
#pragma unroll
        for (int j = 0; j < 8; j++) gt[(coff + j) * 72 + ml] = gv[j];
    }
    __syncthreads();
#pragma unroll
    for (int i = 0; i < 4; i++) {
        int qq = tid + i * 256;
        int ci = qq >> 3, moff = (qq & 7) * 8;
        *(int4*)&gPT[((size_t)(b * CI) + ci) * MP + mt * 64 + moff] = *(const int4*)&gt[ci * 72 + moff];
    }
}

// ---------------- flash attention: y[b][n][ci] ----------------
// v5: swapped QK^T at 32x32x16 (S = mfma(K, Q) -> q cols lane-local), softmax + P fully
//     in registers (T12). 4 waves x 32 q, QBLK=128, grid (8, 49).
//     P->A repack: hi=0 lane needs m{0..7} = own a0,a1 + partner b0,b1;
//                  hi=1 lane needs m{8..15} = partner b2,b3 + own a2,a3.
__global__ __launch_bounds__(256, 2) void k_attn(const f16* __restrict__ q,
                                                 const f16* __restrict__ kk,
                                                 const f16* __restrict__ v,
                                                 f16* __restrict__ y) {
    __shared__ f16 Ks[64 * 128];     // [64 m][128 d] linear, byte ^= ((row&15)<<4) swizzle
    __shared__ f16 Vs[128 * 72];     // [128 ci][64 m] pad 8
    int b = blockIdx.x, n0 = blockIdx.y * 128;
    int tid = threadIdx.x, w = tid >> 6, lane = tid & 63;
    int l31 = lane & 31, hi = lane >> 5;
    int wq = n0 + w * 32;

    // Q fragments (B-operand: col=lane&31=q, k=8*hi+j), pre-scaled by log2(e)
    half8 qf[8];
#pragma unroll
    for (int kc = 0; kc < 8; kc++) {
        qf[kc] = *(const half8*)&q[(size_t)(b * N + wq + l31) * CI + kc * 16 + hi * 8];
#pragma unroll
        for (int j = 0; j < 8; j++) qf[kc][j] *= (f16)1.4426950408889634f;
    }

    f32x16 O0, O1, O2, O3;
#pragma unroll
    for (int i = 0; i < 16; i++) { O0[i] = 0.f; O1[i] = 0.f; O2[i] = 0.f; O3[i] = 0.f; }
    float Osum = 0.f, mi = -1e30f;

    for (int mc = 0; mc < 25; mc++) {
        // ---- stage K (16KB, swizzled) + V (16KB) ----
#pragma unroll
        for (int i = 0; i < 4; i++) {
            int qq = tid + i * 256;
            int kr = qq >> 4, c16 = qq & 15;
            *(int4*)&Ks[kr * 128 + ((c16 ^ (kr & 15)) << 3)] =
                *(const int4*)&kk[((size_t)b * MP + mc * 64 + kr) * CI + c16 * 8];
            int vr = qq >> 3, vc = (qq & 7) * 8;
            *(int4*)&Vs[vr * 72 + vc] = *(const int4*)&v[((size_t)(b * CI) + vr) * MP + mc * 64 + vc];
        }
        __syncthreads();

        // ---- QK^T swapped: S[m][q], 16 MFMA32. A = K rows (lane&31 = m), B = Q regs ----
        f32x16 S0, S1;
#pragma unroll
        for (int i = 0; i < 16; i++) { S0[i] = 0.f; S1[i] = 0.f; }
        __builtin_amdgcn_s_setprio(1);
#pragma unroll
        for (int kc = 0; kc < 8; kc++) {
            int c16 = kc * 2 + hi;
            half8 a0 = *(const half8*)&Ks[l31 * 128 + ((c16 ^ (l31 & 15)) << 3)];
            half8 a1 = *(const half8*)&Ks[(32 + l31) * 128 + ((c16 ^ ((32 + l31) & 15)) << 3)];
            S0 = MFMA32(a0, qf[kc], S0);
            S1 = MFMA32(a1, qf[kc], S1);
        }
        __builtin_amdgcn_s_setprio(0);

        // ---- in-register online softmax (log2 domain). q = lane&31; m spread over regs+hi ----
        float vm = fmaxf(S0[0], S1[0]);
#pragma unroll
        for (int i = 1; i < 16; i++) vm = fmaxf(vm, fmaxf(S0[i], S1[i]));
        vm = fmaxf(vm, __shfl_xor(vm, 32));
        if (__ballot(vm > mi + 8.f)) {              // defer-rescale; wave-uniform
            float mnew = fmaxf(mi, vm);
            float alpha = __builtin_amdgcn_exp2f(mi - mnew);
            mi = mnew;
            Osum *= alpha;
#pragma unroll
            for (int r = 0; r < 16; r++) {          // alpha for O-row q_r via lane read
                int qr = (r & 3) + 8 * (r >> 2) + 4 * hi;
                float al = __shfl(alpha, qr);
                O0[r] *= al; O1[r] *= al; O2[r] *= al; O3[r] *= al;
            }
        }
#pragma unroll
        for (int i = 0; i < 16; i++) {
            S0[i] = __builtin_amdgcn_exp2f(S0[i] - mi);   // bounded by 2^8
            S1[i] = __builtin_amdgcn_exp2f(S1[i] - mi);
        }
        if (mc == 24) {                             // m 1568..1599 is zero-pad (mt==1 half)
#pragma unroll
            for (int i = 0; i < 16; i++) S1[i] = 0.f;
        }
        float ts = 0.f;
#pragma unroll
        for (int i = 0; i < 16; i++) ts += S0[i] + S1[i];
        ts += __shfl_xor(ts, 32);
        Osum += ts;

        // ---- P -> A-fragments (cvt_pk + half-swap + select), PV: 16 MFMA32 ----
        __builtin_amdgcn_s_setprio(1);
#define PV_CHUNK(SV, RB, KC)                                                              \
        {                                                                                 \
            int a0 = pk2(SV[RB + 0], SV[RB + 1]);                                         \
            int a1 = pk2(SV[RB + 2], SV[RB + 3]);                                         \
            int a2 = pk2(SV[RB + 4], SV[RB + 5]);                                         \
            int a3 = pk2(SV[RB + 6], SV[RB + 7]);                                         \
            int b0 = __shfl_xor(a0, 32), b1 = __shfl_xor(a1, 32);                         \
            int b2 = __shfl_xor(a2, 32), b3 = __shfl_xor(a3, 32);                         \
            union { int4 i4; half8 h8; } u;                                               \
            u.i4.x = hi ? b2 : a0; u.i4.y = hi ? b3 : a1;                                 \
            u.i4.z = hi ? a2 : b0; u.i4.w = hi ? a3 : b1;                                 \
            O0 = MFMA32(u.h8, *(const half8*)&Vs[(0 * 32 + l31) * 72 + KC * 16 + hi * 8], O0); \
            O1 = MFMA32(u.h8, *(const half8*)&Vs[(1 * 32 + l31) * 72 + KC * 16 + hi * 8], O1); \
            O2 = MFMA32(u.h8, *(const half8*)&Vs[(2 * 32 + l31) * 72 + KC * 16 + hi * 8], O2); \
            O3 = MFMA32(u.h8, *(const half8*)&Vs[(3 * 32 + l31) * 72 + KC * 16 + hi * 8], O3); \
        }
        PV_CHUNK(S0, 0, 0)
        PV_CHUNK(S0, 8, 1)
        PV_CHUNK(S1, 0, 2)
        PV_CHUNK(S1, 8, 3)
#undef PV_CHUNK
        __builtin_amdgcn_s_setprio(0);
        __syncthreads();
    }

    // ---- epilogue: y[q][ci] = O / Osum(q). O row q_r = (r&3)+8*(r>>2)+4*hi, col = lane&31 ----
#pragma unroll
    for (int r = 0; r < 16; r++) {
        int qr = (r & 3) + 8 * (r >> 2) + 4 * hi;
        float inv = 1.0f / __shfl(Osum, qr);
        size_t base = (size_t)(b * N + wq + qr) * CI + l31;
        y[base]      = (f16)(O0[r] * inv);
        y[base + 32] = (f16)(O1[r] * inv);
        y[base + 64] = (f16)(O2[r] * inv);
        y[base + 96] = (f16)(O3[r] * inv);
    }
}

// ---------------- final: out[b][c][n] = W.y + Wb + x ----------------
// grid (8, 98, 2): b = blockIdx.x, n-tile = blockIdx.y, c-half = blockIdx.z
__global__ __launch_bounds__(256) void k_final(const f16* __restrict__ y,
                                               const f16* __restrict__ Ww,
                                               const float* __restrict__ Wb,
                                               const float* __restrict__ x,
                                               float* __restrict__ out) {
    __shared__ f16 ys[64 * 136];    // [64 n][128 ci] pad 8
    __shared__ f16 Ws[128 * 136];   // [128 c][128 ci] pad 8
    int b = blockIdx.x, ch = blockIdx.z, n0 = blockIdx.y * 64;
    int tid = threadIdx.x, w = tid >> 6, lane = tid & 63, ln = lane & 15, quad = lane >> 4;
#pragma unroll
    for (int i = 0; i < 4; i++) {
        int qq = tid + i * 256; int row = qq >> 4, coff = (qq & 15) * 8;
        *(int4*)&ys[row * 136 + coff] =
            *(const int4*)&y[(size_t)(b * N + n0 + row) * CI + coff];
    }
#pragma unroll
    for (int i = 0; i < 8; i++) {
        int qq = tid + i * 256; int row = qq >> 4, coff = (qq & 15) * 8;
        *(int4*)&Ws[row * 136 + coff] =
            *(const int4*)&Ww[(size_t)(ch * 128 + row) * CI + coff];
    }
    __syncthreads();
    f32x4 acc[2][4];
#pragma unroll
    for (int rb = 0; rb < 2; rb++)
#pragma unroll
        for (int nb = 0; nb < 4; nb++) acc[rb][nb] = (f32x4){0.f, 0.f, 0.f, 0.f};
#pragma unroll
    for (int ks = 0; ks < 4; ks++) {
        half8 a0 = *(const half8*)&Ws[(w * 32 + ln) * 136 + ks * 32 + quad * 8];
        half8 a1 = *(const half8*)&Ws[(w * 32 + 16 + ln) * 136 + ks * 32 + quad * 8];
#pragma unroll
        for (int nb = 0; nb < 4; nb++) {
            half8 bf = *(const half8*)&ys[(nb * 16 + ln) * 136 + ks * 32 + quad * 8];
            acc[0][nb] = MFMA16(a0, bf, acc[0][nb]);
            acc[1][nb] = MFMA16(a1, bf, acc[1][nb]);
        }
    }
#pragma unroll
    for (int rb = 0; rb < 2; rb++) {
        int cbase = ch * 128 + w * 32 + rb * 16 + quad * 4;
#pragma unroll
        for (int nb = 0; nb < 4; nb++) {
#pragma unroll
            for (int r = 0; r < 4; r++) {
                int c = cbase + r;
                size_t addr = (size_t)(b * C + c) * N + n0 + nb * 16 + ln;
                out[addr] = acc[rb][nb][r] + Wb[c] + x[addr];
            }
        }
    }
}

extern "C" void kernel_launch(void* const* d_in, const int* in_sizes, int n_in,
                              void* d_out, int out_size, void* d_ws, size_t ws_size,
                              hipStream_t stream) {
    const float* x  = (const float*)d_in[0];
    const float* gw = (const float*)d_in[1];
    const float* gb = (const float*)d_in[2];
    const float* tw = (const float*)d_in[3];
    const float* tb = (const float*)d_in[4];
    const float* pw = (const float*)d_in[5];
    const float* pb = (const float*)d_in[6];
    const float* Ww = (const float*)d_in[7];
    const float* Wb = (const float*)d_in[8];
    float* out = (float*)d_out;
    f16* ws = (f16*)d_ws;

    f16* Q    = ws + oQ;
    f16* phiF = ws + oPF;
    f16* gF   = ws + oGF;
    f16* phiP = ws + oPP;
    f16* gPT  = ws + oGT;
    f16* Y    = ws + oPF;   // alias: phiF dead after k_pool
    f16* w16  = ws + oW;

    k_prep<<<512, 256, 0, stream>>>(tw, pw, gw, Ww, w16);
    k_proj3<<<dim3(8, 98), 256, 0, stream>>>(x, w16, tb, pb, gb, Q, phiF, gF);
    k_pool<<<dim3(8, 25), 256, 0, stream>>>(phiF, gF, phiP, gPT);
    k_attn<<<dim3(8, 49), 256, 0, stream>>>(Q, phiP, gPT, Y);
    k_final<<<dim3(8, 98, 2), 256, 0, stream>>>(Y, w16 + 98304, Wb, x, out);
    (void)in_sizes; (void)n_in; (void)out_size; (void)ws_size;
}

// Round 9
// 228.488 us; speedup vs baseline: 1.8483x; 1.0039x over previous
//
#include <hip/hip_runtime.h>

typedef _Float16 f16;
typedef f16 half8 __attribute__((ext_vector_type(8)));
typedef __fp16 fp16x2 __attribute__((ext_vector_type(2)));
typedef float f32x4 __attribute__((ext_vector_type(4)));
typedef float f32x16 __attribute__((ext_vector_type(16)));

#define MFMA16(a, b, c) __builtin_amdgcn_mfma_f32_16x16x32_f16((a), (b), (c), 0, 0, 0)
#define MFMA32(a, b, c) __builtin_amdgcn_mfma_f32_32x32x16_f16((a), (b), (c), 0, 0, 0)

static constexpr int B = 8, C = 256, CI = 128, N = 6272, M = 1568, MP = 1600;

// f16-element offsets into workspace (~71 MB). Y aliases phiF (consumed by k_pool).
static constexpr size_t oXT = 0;                         // (unused since transpose fused)
static constexpr size_t oQ  = (size_t)B * N * C;         // [B][N][CI]  theta
static constexpr size_t oPF = oQ  + (size_t)B * N * CI;  // [B][N][CI]  phi full-res; later Y
static constexpr size_t oGF = oPF + (size_t)B * N * CI;  // [B][N][CI]  g full-res
static constexpr size_t oPP = oGF + (size_t)B * N * CI;  // [B][MP][CI] phi pooled (K), pad zeroed
static constexpr size_t oGT = oPP + (size_t)B * MP * CI; // [B][CI][MP] g pooled transposed (V), pad zeroed
static constexpr size_t oW  = oGT + (size_t)B * MP * CI; // 4*32768 f16 weights: theta|phi|g|W

static __device__ __forceinline__ half8 hmax8(half8 a, half8 b) {
    half8 r;
#pragma unroll
    for (int j = 0; j < 8; j++) r[j] = a[j] > b[j] ? a[j] : b[j];
    return r;
}

static __device__ __forceinline__ int pk2(float a, float b) {
    union { fp16x2 h; int i; } u;
    u.h = __builtin_amdgcn_cvt_pkrtz(a, b);
    return u.i;
}

// ---------------- weight cast fp32 -> f16 ----------------
__global__ void k_prep(const float* tw, const float* pw, const float* gw,
                       const float* Ww, f16* dst) {
    int i = blockIdx.x * 256 + threadIdx.x;   // 0..131071
    int s = i >> 15, j = i & 32767;
    float v;
    if (s == 0) v = tw[j];
    else if (s == 1) v = pw[j];
    else if (s == 2) v = gw[j];
    else v = Ww[j];
    dst[i] = (f16)v;
}

// ---------------- fused transpose + projection GEMM ----------------
// {theta,phi,g}[b][n][ci] = x[b][:][n] . w_p + bias_p.  x read in native [c][n] layout
// (coalesced), cast to f16, scattered into xs[n][c].  grid (8, 98).
__global__ __launch_bounds__(256, 2) void k_proj3(const float* __restrict__ x,
                                                  const f16* __restrict__ w16,
                                                  const float* __restrict__ tb,
                                                  const float* __restrict__ pb,
                                                  const float* __restrict__ gb,
                                                  f16* __restrict__ outQ,
                                                  f16* __restrict__ outP,
                                                  f16* __restrict__ outG) {
    __shared__ f16 xs[64 * 72];        // [64 n][64 k] pad 8
    __shared__ f16 ws[3 * 128 * 72];   // per proj: [128 ci][64 k] pad 8
    int b = blockIdx.x, n0 = blockIdx.y * 64;
    int tid = threadIdx.x, w = tid >> 6, lane = tid & 63, ln = lane & 15, quad = lane >> 4;
    f32x4 acc[3][8];
#pragma unroll
    for (int p = 0; p < 3; p++)
#pragma unroll
        for (int cb = 0; cb < 8; cb++) acc[p][cb] = (f32x4){0.f, 0.f, 0.f, 0.f};

    for (int kc = 0; kc < 4; kc++) {
#pragma unroll
        for (int i = 0; i < 16; i++) {
            int qq = tid + i * 256;            // 0..4095
            int nn = qq & 63, cc = qq >> 6;    // lanes -> consecutive n (coalesced)
            float v = x[(size_t)(b * C + kc * 64 + cc) * N + n0 + nn];
            xs[nn * 72 + cc] = (f16)v;
        }
#pragma unroll
        for (int p = 0; p < 3; p++)
#pragma unroll
            for (int i = 0; i < 4; i++) {
                int qq = tid + i * 256;        // 0..1023
                int row = qq >> 3, coff = (qq & 7) * 8;
                *(int4*)&ws[p * 9216 + row * 72 + coff] =
                    *(const int4*)&w16[(size_t)p * 32768 + (size_t)row * C + kc * 64 + coff];
            }
        __syncthreads();
#pragma unroll
        for (int ks = 0; ks < 2; ks++) {
            half8 a = *(const half8*)&xs[(w * 16 + ln) * 72 + ks * 32 + quad * 8];
#pragma unroll
            for (int p = 0; p < 3; p++)
#pragma unroll
                for (int cb = 0; cb < 8; cb++) {
                    half8 bf = *(const half8*)&ws[p * 9216 + (cb * 16 + ln) * 72 + ks * 32 + quad * 8];
                    acc[p][cb] = MFMA16(a, bf, acc[p][cb]);
                }
        }
        __syncthreads();
    }
#pragma unroll
    for (int p = 0; p < 3; p++) {
        const float* bias = (p == 0) ? tb : (p == 1) ? pb : gb;
        f16* out = (p == 0) ? outQ : (p == 1) ? outP : outG;
#pragma unroll
        for (int cb = 0; cb < 8; cb++) {
            float bv = bias[cb * 16 + ln];
#pragma unroll
            for (int r = 0; r < 4; r++) {
                int n = n0 + w * 16 + quad * 4 + r;
                out[(size_t)(b * N + n) * CI + cb * 16 + ln] = (f16)(acc[p][cb][r] + bv);
            }
        }
    }
}

// ---------------- 2x2 spatial maxpool; K as [m][ci], V as [ci][m] ----------------
// grid (8, 25): b = blockIdx.x
__global__ __launch_bounds__(256) void k_pool(const f16* __restrict__ phiF, const f16* __restrict__ gF,
                                              f16* __restrict__ phiP, f16* __restrict__ gPT) {
    __shared__ f16 gt[128 * 72];   // [128 ci][64 m] pad 8
    int b = blockIdx.x, mt = blockIdx.y;   // mt 0..24 over MP=1600
    int tid = threadIdx.x;
#pragma unroll
    for (int i = 0; i < 4; i++) {
        int qq = tid + i * 256;            // 0..1023
        int ml = qq >> 4, coff = (qq & 15) * 8;
        int m = mt * 64 + ml;
        half8 pv, gv;
        if (m < M) {
            int t = m / 196, rr = m % 196, hp = rr / 14, wp = rr % 14;
            int nb = t * 784 + hp * 56 + wp * 2;
            size_t base = ((size_t)(b * N) + nb) * CI + coff;
            half8 p0 = *(const half8*)&phiF[base];
            half8 p1 = *(const half8*)&phiF[base + CI];
            half8 p2 = *(const half8*)&phiF[base + 28 * CI];
            half8 p3 = *(const half8*)&phiF[base + 29 * CI];
            pv = hmax8(hmax8(p0, p1), hmax8(p2, p3));
            half8 g0 = *(const half8*)&gF[base];
            half8 g1 = *(const half8*)&gF[base + CI];
            half8 g2 = *(const half8*)&gF[base + 28 * CI];
            half8 g3 = *(const half8*)&gF[base + 29 * CI];
            gv = hmax8(hmax8(g0, g1), hmax8(g2, g3));
        } else {
#pragma unroll
            for (int j = 0; j < 8; j++) { pv[j] = (f16)0.f; gv[j] = (f16)0.f; }
        }
        *(half8*)&phiP[((size_t)b * MP + m) * CI + coff] = pv;
#pragma unroll
        for (int j = 0; j < 8; j++) gt[(coff + j) * 72 + ml] = gv[j];
    }
    __syncthreads();
#pragma unroll
    for (int i = 0; i < 4; i++) {
        int qq = tid + i * 256;
        int ci = qq >> 3, moff = (qq & 7) * 8;
        *(int4*)&gPT[((size_t)(b * CI) + ci) * MP + mt * 64 + moff] = *(const int4*)&gt[ci * 72 + moff];
    }
}

// ---------------- flash attention: y[b][n][ci] ----------------
// v6: v5 structure (swapped QK^T 32x32, in-reg softmax/P) + double-buffered K/V staging via
//     global_load_lds with pre-swizzled SOURCE addresses (linear LDS dest, rule #21).
//     Loop: issue STAGE(buf^1, mc+1) -> compute buf -> vmcnt(0) -> ONE barrier.
__global__ __launch_bounds__(256, 2) void k_attn(const f16* __restrict__ q,
                                                 const f16* __restrict__ kk,
                                                 const f16* __restrict__ v,
                                                 f16* __restrict__ y) {
    __shared__ f16 Ks[2][64 * 128];   // [m][d]  16KB per buf
    __shared__ f16 Vs[2][128 * 64];   // [ci][m] 16KB per buf
    int b = blockIdx.x, n0 = blockIdx.y * 128;
    int tid = threadIdx.x, w = tid >> 6, lane = tid & 63;
    int l31 = lane & 31, hi = lane >> 5;
    int wq = n0 + w * 32;

#define STAGE(BUF, MC)                                                                     \
    {                                                                                      \
        _Pragma("unroll")                                                                  \
        for (int i = 0; i < 4; i++) {                                                      \
            int kr = w * 16 + i * 4 + (lane >> 4);                                         \
            const f16* kg = kk + ((size_t)b * MP + (MC) * 64 + kr) * CI                    \
                            + (((lane & 15) ^ (kr & 15)) << 3);                            \
            __builtin_amdgcn_global_load_lds(                                              \
                (const __attribute__((address_space(1))) void*)kg,                         \
                (__attribute__((address_space(3))) void*)&Ks[BUF][w * 2048 + i * 512],     \
                16, 0, 0);                                                                 \
            int vr = w * 32 + i * 8 + (lane >> 3);                                         \
            const f16* vg = v + ((size_t)(b * CI) + vr) * MP + (MC) * 64                   \
                            + (((lane & 7) ^ (vr & 7)) << 3);                              \
            __builtin_amdgcn_global_load_lds(                                              \
                (const __attribute__((address_space(1))) void*)vg,                         \
                (__attribute__((address_space(3))) void*)&Vs[BUF][w * 2048 + i * 512],     \
                16, 0, 0);                                                                 \
        }                                                                                  \
    }

    // prologue: stage tile 0
    STAGE(0, 0)
    // Q fragments (B-operand: col=lane&31=q, k=8*hi+j), pre-scaled by log2(e)
    half8 qf[8];
#pragma unroll
    for (int kc = 0; kc < 8; kc++) {
        qf[kc] = *(const half8*)&q[(size_t)(b * N + wq + l31) * CI + kc * 16 + hi * 8];
#pragma unroll
        for (int j = 0; j < 8; j++) qf[kc][j] *= (f16)1.4426950408889634f;
    }

    f32x16 O0, O1, O2, O3;
#pragma unroll
    for (int i = 0; i < 16; i++) { O0[i] = 0.f; O1[i] = 0.f; O2[i] = 0.f; O3[i] = 0.f; }
    float Osum = 0.f, mi = -1e30f;

    asm volatile("s_waitcnt vmcnt(0)" ::: "memory");
    __syncthreads();

    int buf = 0;
    for (int mc = 0; mc < 25; mc++) {
        // ---- issue next tile's loads (fly under this tile's compute) ----
        if (mc < 24) STAGE(buf ^ 1, mc + 1)

        // ---- QK^T swapped: S[m][q], 16 MFMA32. A = K rows (lane&31 = m), B = Q regs ----
        f32x16 S0, S1;
#pragma unroll
        for (int i = 0; i < 16; i++) { S0[i] = 0.f; S1[i] = 0.f; }
        __builtin_amdgcn_s_setprio(1);
#pragma unroll
        for (int kc = 0; kc < 8; kc++) {
            int c16 = kc * 2 + hi;
            half8 a0 = *(const half8*)&Ks[buf][l31 * 128 + ((c16 ^ (l31 & 15)) << 3)];
            half8 a1 = *(const half8*)&Ks[buf][(32 + l31) * 128 + ((c16 ^ (l31 & 15)) << 3)];
            S0 = MFMA32(a0, qf[kc], S0);
            S1 = MFMA32(a1, qf[kc], S1);
        }
        __builtin_amdgcn_s_setprio(0);

        // ---- in-register online softmax (log2 domain). q = lane&31 ----
        float vm = fmaxf(S0[0], S1[0]);
#pragma unroll
        for (int i = 1; i < 16; i++) vm = fmaxf(vm, fmaxf(S0[i], S1[i]));
        vm = fmaxf(vm, __shfl_xor(vm, 32));
        if (__ballot(vm > mi + 8.f)) {              // defer-rescale; wave-uniform
            float mnew = fmaxf(mi, vm);
            float alpha = __builtin_amdgcn_exp2f(mi - mnew);
            mi = mnew;
            Osum *= alpha;
#pragma unroll
            for (int r = 0; r < 16; r++) {
                int qr = (r & 3) + 8 * (r >> 2) + 4 * hi;
                float al = __shfl(alpha, qr);
                O0[r] *= al; O1[r] *= al; O2[r] *= al; O3[r] *= al;
            }
        }
#pragma unroll
        for (int i = 0; i < 16; i++) {
            S0[i] = __builtin_amdgcn_exp2f(S0[i] - mi);   // bounded by 2^8
            S1[i] = __builtin_amdgcn_exp2f(S1[i] - mi);
        }
        if (mc == 24) {                             // m 1568..1599 is zero-pad (mt==1 half)
#pragma unroll
            for (int i = 0; i < 16; i++) S1[i] = 0.f;
        }
        float ts = 0.f;
#pragma unroll
        for (int i = 0; i < 16; i++) ts += S0[i] + S1[i];
        ts += __shfl_xor(ts, 32);
        Osum += ts;

        // ---- P -> A-fragments (cvt_pk + half-swap + select), PV: 16 MFMA32 ----
        __builtin_amdgcn_s_setprio(1);
#define PV_CHUNK(SV, RB, KC)                                                                   \
        {                                                                                      \
            int a0 = pk2(SV[RB + 0], SV[RB + 1]);                                              \
            int a1 = pk2(SV[RB + 2], SV[RB + 3]);                                              \
            int a2 = pk2(SV[RB + 4], SV[RB + 5]);                                              \
            int a3 = pk2(SV[RB + 6], SV[RB + 7]);                                              \
            int b0 = __shfl_xor(a0, 32), b1 = __shfl_xor(a1, 32);                              \
            int b2 = __shfl_xor(a2, 32), b3 = __shfl_xor(a3, 32);                              \
            union { int4 i4; half8 h8; } u;                                                    \
            u.i4.x = hi ? b2 : a0; u.i4.y = hi ? b3 : a1;                                      \
            u.i4.z = hi ? a2 : b0; u.i4.w = hi ? a3 : b1;                                      \
            O0 = MFMA32(u.h8, *(const half8*)&Vs[buf][(0 * 32 + l31) * 64 + ((((KC) * 2 + hi) ^ (l31 & 7)) << 3)], O0); \
            O1 = MFMA32(u.h8, *(const half8*)&Vs[buf][(1 * 32 + l31) * 64 + ((((KC) * 2 + hi) ^ (l31 & 7)) << 3)], O1); \
            O2 = MFMA32(u.h8, *(const half8*)&Vs[buf][(2 * 32 + l31) * 64 + ((((KC) * 2 + hi) ^ (l31 & 7)) << 3)], O2); \
            O3 = MFMA32(u.h8, *(const half8*)&Vs[buf][(3 * 32 + l31) * 64 + ((((KC) * 2 + hi) ^ (l31 & 7)) << 3)], O3); \
        }
        PV_CHUNK(S0, 0, 0)
        PV_CHUNK(S0, 8, 1)
        PV_CHUNK(S1, 0, 2)
        PV_CHUNK(S1, 8, 3)
#undef PV_CHUNK
        __builtin_amdgcn_s_setprio(0);

        // ---- next-tile loads landed?  one barrier per iter ----
        asm volatile("s_waitcnt vmcnt(0)" ::: "memory");
        __syncthreads();
        buf ^= 1;
    }
#undef STAGE

    // ---- epilogue: y[q][ci] = O / Osum(q) ----
#pragma unroll
    for (int r = 0; r < 16; r++) {
        int qr = (r & 3) + 8 * (r >> 2) + 4 * hi;
        float inv = 1.0f / __shfl(Osum, qr);
        size_t base = (size_t)(b * N + wq + qr) * CI + l31;
        y[base]      = (f16)(O0[r] * inv);
        y[base + 32] = (f16)(O1[r] * inv);
        y[base + 64] = (f16)(O2[r] * inv);
        y[base + 96] = (f16)(O3[r] * inv);
    }
}

// ---------------- final: out[b][c][n] = W.y + Wb + x ----------------
// grid (8, 98, 2): b = blockIdx.x, n-tile = blockIdx.y, c-half = blockIdx.z
__global__ __launch_bounds__(256) void k_final(const f16* __restrict__ y,
                                               const f16* __restrict__ Ww,
                                               const float* __restrict__ Wb,
                                               const float* __restrict__ x,
                                               float* __restrict__ out) {
    __shared__ f16 ys[64 * 136];    // [64 n][128 ci] pad 8
    __shared__ f16 Ws[128 * 136];   // [128 c][128 ci] pad 8
    int b = blockIdx.x, ch = blockIdx.z, n0 = blockIdx.y * 64;
    int tid = threadIdx.x, w = tid >> 6, lane = tid & 63, ln = lane & 15, quad = lane >> 4;
#pragma unroll
    for (int i = 0; i < 4; i++) {
        int qq = tid + i * 256; int row = qq >> 4, coff = (qq & 15) * 8;
        *(int4*)&ys[row * 136 + coff] =
            *(const int4*)&y[(size_t)(b * N + n0 + row) * CI + coff];
    }
#pragma unroll
    for (int i = 0; i < 8; i++) {
        int qq = tid + i * 256; int row = qq >> 4, coff = (qq & 15) * 8;
        *(int4*)&Ws[row * 136 + coff] =
            *(const int4*)&Ww[(size_t)(ch * 128 + row) * CI + coff];
    }
    __syncthreads();
    f32x4 acc[2][4];
#pragma unroll
    for (int rb = 0; rb < 2; rb++)
#pragma unroll
        for (int nb = 0; nb < 4; nb++) acc[rb][nb] = (f32x4){0.f, 0.f, 0.f, 0.f};
#pragma unroll
    for (int ks = 0; ks < 4; ks++) {
        half8 a0 = *(const half8*)&Ws[(w * 32 + ln) * 136 + ks * 32 + quad * 8];
        half8 a1 = *(const half8*)&Ws[(w * 32 + 16 + ln) * 136 + ks * 32 + quad * 8];
#pragma unroll
        for (int nb = 0; nb < 4; nb++) {
            half8 bf = *(const half8*)&ys[(nb * 16 + ln) * 136 + ks * 32 + quad * 8];
            acc[0][nb] = MFMA16(a0, bf, acc[0][nb]);
            acc[1][nb] = MFMA16(a1, bf, acc[1][nb]);
        }
    }
#pragma unroll
    for (int rb = 0; rb < 2; rb++) {
        int cbase = ch * 128 + w * 32 + rb * 16 + quad * 4;
#pragma unroll
        for (int nb = 0; nb < 4; nb++) {
#pragma unroll
            for (int r = 0; r < 4; r++) {
                int c = cbase + r;
                size_t addr = (size_t)(b * C + c) * N + n0 + nb * 16 + ln;
                out[addr] = acc[rb][nb][r] + Wb[c] + x[addr];
            }
        }
    }
}

extern "C" void kernel_launch(void* const* d_in, const int* in_sizes, int n_in,
                              void* d_out, int out_size, void* d_ws, size_t ws_size,
                              hipStream_t stream) {
    const float* x  = (const float*)d_in[0];
    const float* gw = (const float*)d_in[1];
    const float* gb = (const float*)d_in[2];
    const float* tw = (const float*)d_in[3];
    const float* tb = (const float*)d_in[4];
    const float* pw = (const float*)d_in[5];
    const float* pb = (const float*)d_in[6];
    const float* Ww = (const float*)d_in[7];
    const float* Wb = (const float*)d_in[8];
    float* out = (float*)d_out;
    f16* ws = (f16*)d_ws;

    f16* Q    = ws + oQ;
    f16* phiF = ws + oPF;
    f16* gF   = ws + oGF;
    f16* phiP = ws + oPP;
    f16* gPT  = ws + oGT;
    f16* Y    = ws + oPF;   // alias: phiF dead after k_pool
    f16* w16  = ws + oW;

    k_prep<<<512, 256, 0, stream>>>(tw, pw, gw, Ww, w16);
    k_proj3<<<dim3(8, 98), 256, 0, stream>>>(x, w16, tb, pb, gb, Q, phiF, gF);
    k_pool<<<dim3(8, 25), 256, 0, stream>>>(phiF, gF, phiP, gPT);
    k_attn<<<dim3(8, 49), 256, 0, stream>>>(Q, phiP, gPT, Y);
    k_final<<<dim3(8, 98, 2), 256, 0, stream>>>(Y, w16 + 98304, Wb, x, out);
    (void)in_sizes; (void)n_in; (void)out_size; (void)ws_size;
}